// Round 7
// baseline (37266.010 us; speedup 1.0000x reference)
//
#include <hip/hip_runtime.h>
#include <hip/hip_bf16.h>

// ---------------- utility kernels ------------------------------------------
__global__ void zero_u32(unsigned int* __restrict__ p, long long n)
{
    long long i = (long long)blockIdx.x * 256 + threadIdx.x;
    if (i < n) p[i] = 0u;
}

__global__ void sentinel_f32(float* __restrict__ p, long long n, float v)
{
    long long i = (long long)blockIdx.x * 256 + threadIdx.x;
    if (i < n) p[i] = v;
}

__device__ __forceinline__ float4 load_f4_guard(const float* base, int gm, int M, int K, int kb)
{
    float4 v = make_float4(0.f, 0.f, 0.f, 0.f);
    if (gm < M) {
        const float* p = base + (size_t)gm * K + kb;
        if (kb + 4 <= K) v = *(const float4*)p;
        else {
            if (kb     < K) v.x = p[0];
            if (kb + 1 < K) v.y = p[1];
            if (kb + 2 < K) v.z = p[2];
            if (kb + 3 < K) v.w = p[3];
        }
    }
    return v;
}

// ---------------- multi-segment GEMM, double-buffered ------------------------
// C[M,128] = act(A[M,K] @ W[128,K]^T + bias?), up to 4 independent segments.
// 128x128 tile, BK=16, 8x8/thread, 2-deep LDS pipeline (1 barrier / K-step).
struct GSeg {
    const float* A; const float* W; const float* bias; float* C;
    int M; int K; int bend;   // bend = exclusive block-id end of this segment
};
struct GParams { GSeg s[4]; };

template<bool RELU>
__global__ __launch_bounds__(256, 4) void gemm_multi(GParams P, int nseg)
{
    __shared__ float As[2][16][132];
    __shared__ float Ws[2][16][132];
    const int b = blockIdx.x;
    int si = 0, bbeg = 0;
    while (si + 1 < nseg && b >= P.s[si].bend) { bbeg = P.s[si].bend; ++si; }
    const GSeg S = P.s[si];
    const int tid = threadIdx.x;
    const int tx = tid & 15, ty = tid >> 4;
    const int row0 = (b - bbeg) * 128;
    const int r  = tid >> 2;          // 0..63
    const int k4 = (tid & 3) * 4;     // 0,4,8,12
    const int nsteps = (S.K + 15) >> 4;

    float4 pa[2], pw[2];
    // prefetch step 0
#pragma unroll
    for (int c = 0; c < 2; ++c) {
        int rr = r + c * 64;
        pa[c] = load_f4_guard(S.A, row0 + rr, S.M, S.K, k4);
        pw[c] = load_f4_guard(S.W, rr, 128, S.K, k4);
    }
#pragma unroll
    for (int c = 0; c < 2; ++c) {
        int rr = r + c * 64;
        As[0][k4 + 0][rr] = pa[c].x; As[0][k4 + 1][rr] = pa[c].y;
        As[0][k4 + 2][rr] = pa[c].z; As[0][k4 + 3][rr] = pa[c].w;
        Ws[0][k4 + 0][rr] = pw[c].x; Ws[0][k4 + 1][rr] = pw[c].y;
        Ws[0][k4 + 2][rr] = pw[c].z; Ws[0][k4 + 3][rr] = pw[c].w;
    }
    __syncthreads();

    float acc[8][8] = {};
    for (int s = 0; s < nsteps; ++s) {
        const int cur = s & 1;
        const bool more = (s + 1 < nsteps);
        if (more) {
            int kb = (s + 1) * 16 + k4;
#pragma unroll
            for (int c = 0; c < 2; ++c) {
                int rr = r + c * 64;
                pa[c] = load_f4_guard(S.A, row0 + rr, S.M, S.K, kb);
                pw[c] = load_f4_guard(S.W, rr, 128, S.K, kb);
            }
        }
#pragma unroll
        for (int kk = 0; kk < 16; ++kk) {
            float4 a0 = *(const float4*)&As[cur][kk][ty * 4];
            float4 a1 = *(const float4*)&As[cur][kk][64 + ty * 4];
            float4 w0 = *(const float4*)&Ws[cur][kk][tx * 4];
            float4 w1 = *(const float4*)&Ws[cur][kk][64 + tx * 4];
            float a[8] = {a0.x, a0.y, a0.z, a0.w, a1.x, a1.y, a1.z, a1.w};
            float w[8] = {w0.x, w0.y, w0.z, w0.w, w1.x, w1.y, w1.z, w1.w};
#pragma unroll
            for (int i = 0; i < 8; ++i)
#pragma unroll
                for (int j = 0; j < 8; ++j)
                    acc[i][j] += a[i] * w[j];
        }
        if (more) {
            const int nxt = cur ^ 1;
#pragma unroll
            for (int c = 0; c < 2; ++c) {
                int rr = r + c * 64;
                As[nxt][k4 + 0][rr] = pa[c].x; As[nxt][k4 + 1][rr] = pa[c].y;
                As[nxt][k4 + 2][rr] = pa[c].z; As[nxt][k4 + 3][rr] = pa[c].w;
                Ws[nxt][k4 + 0][rr] = pw[c].x; Ws[nxt][k4 + 1][rr] = pw[c].y;
                Ws[nxt][k4 + 2][rr] = pw[c].z; Ws[nxt][k4 + 3][rr] = pw[c].w;
            }
            __syncthreads();
        }
    }
    float bs[8];
    if (S.bias) {
#pragma unroll
        for (int j = 0; j < 4; ++j) {
            bs[j]     = S.bias[tx * 4 + j];
            bs[j + 4] = S.bias[64 + tx * 4 + j];
        }
    } else {
#pragma unroll
        for (int j = 0; j < 8; ++j) bs[j] = 0.f;
    }
#pragma unroll
    for (int i = 0; i < 8; ++i) {
        int rr = (i < 4) ? (ty * 4 + i) : (64 + ty * 4 + i - 4);
        int gm = row0 + rr;
        if (gm >= S.M) continue;
#pragma unroll
        for (int jh = 0; jh < 2; ++jh) {
            float4 v;
            v.x = acc[i][jh * 4 + 0] + bs[jh * 4 + 0];
            v.y = acc[i][jh * 4 + 1] + bs[jh * 4 + 1];
            v.z = acc[i][jh * 4 + 2] + bs[jh * 4 + 2];
            v.w = acc[i][jh * 4 + 3] + bs[jh * 4 + 3];
            if (RELU) {
                v.x = fmaxf(v.x, 0.f); v.y = fmaxf(v.y, 0.f);
                v.z = fmaxf(v.z, 0.f); v.w = fmaxf(v.w, 0.f);
            }
            *(float4*)&S.C[(size_t)gm * 128 + jh * 64 + tx * 4] = v;
        }
    }
}

// ---------------- BM=64 GEMM, double-buffered, K=128 fixed -------------------
__global__ __launch_bounds__(256, 4) void gemm64(
    const float* __restrict__ A, const float* __restrict__ W,
    const float* __restrict__ bias, float* __restrict__ C, int M)
{
    __shared__ float As[2][16][68];
    __shared__ float Ws[2][16][132];
    const int tid = threadIdx.x;
    const int tx = tid & 15, ty = tid >> 4;
    const int row0 = blockIdx.x * 64;
    const int r  = tid >> 2;
    const int k4 = (tid & 3) * 4;

    float4 pa, pw[2];
    {
        int gm = row0 + r;
        pa = make_float4(0.f, 0.f, 0.f, 0.f);
        if (gm < M) pa = *(const float4*)(A + (size_t)gm * 128 + k4);
        pw[0] = *(const float4*)(W + (size_t)r * 128 + k4);
        pw[1] = *(const float4*)(W + (size_t)(r + 64) * 128 + k4);
    }
    As[0][k4 + 0][r] = pa.x; As[0][k4 + 1][r] = pa.y;
    As[0][k4 + 2][r] = pa.z; As[0][k4 + 3][r] = pa.w;
#pragma unroll
    for (int c = 0; c < 2; ++c) {
        int rr = r + c * 64;
        Ws[0][k4 + 0][rr] = pw[c].x; Ws[0][k4 + 1][rr] = pw[c].y;
        Ws[0][k4 + 2][rr] = pw[c].z; Ws[0][k4 + 3][rr] = pw[c].w;
    }
    __syncthreads();

    float acc[4][8] = {};
#pragma unroll
    for (int s = 0; s < 8; ++s) {
        const int cur = s & 1;
        const bool more = (s < 7);
        if (more) {
            int kb = (s + 1) * 16 + k4;
            int gm = row0 + r;
            pa = make_float4(0.f, 0.f, 0.f, 0.f);
            if (gm < M) pa = *(const float4*)(A + (size_t)gm * 128 + kb);
            pw[0] = *(const float4*)(W + (size_t)r * 128 + kb);
            pw[1] = *(const float4*)(W + (size_t)(r + 64) * 128 + kb);
        }
#pragma unroll
        for (int kk = 0; kk < 16; ++kk) {
            float4 a0 = *(const float4*)&As[cur][kk][ty * 4];
            float4 w0 = *(const float4*)&Ws[cur][kk][tx * 4];
            float4 w1 = *(const float4*)&Ws[cur][kk][64 + tx * 4];
            float a[4] = {a0.x, a0.y, a0.z, a0.w};
            float w[8] = {w0.x, w0.y, w0.z, w0.w, w1.x, w1.y, w1.z, w1.w};
#pragma unroll
            for (int i = 0; i < 4; ++i)
#pragma unroll
                for (int j = 0; j < 8; ++j)
                    acc[i][j] += a[i] * w[j];
        }
        if (more) {
            const int nxt = cur ^ 1;
            As[nxt][k4 + 0][r] = pa.x; As[nxt][k4 + 1][r] = pa.y;
            As[nxt][k4 + 2][r] = pa.z; As[nxt][k4 + 3][r] = pa.w;
#pragma unroll
            for (int c = 0; c < 2; ++c) {
                int rr = r + c * 64;
                Ws[nxt][k4 + 0][rr] = pw[c].x; Ws[nxt][k4 + 1][rr] = pw[c].y;
                Ws[nxt][k4 + 2][rr] = pw[c].z; Ws[nxt][k4 + 3][rr] = pw[c].w;
            }
            __syncthreads();
        }
    }
    float bs[8];
#pragma unroll
    for (int j = 0; j < 4; ++j) {
        bs[j]     = bias ? bias[tx * 4 + j] : 0.f;
        bs[j + 4] = bias ? bias[64 + tx * 4 + j] : 0.f;
    }
#pragma unroll
    for (int i = 0; i < 4; ++i) {
        int gm = row0 + ty * 4 + i;
        if (gm >= M) continue;
#pragma unroll
        for (int jh = 0; jh < 2; ++jh) {
            float4 v;
            v.x = acc[i][jh * 4 + 0] + bs[jh * 4 + 0];
            v.y = acc[i][jh * 4 + 1] + bs[jh * 4 + 1];
            v.z = acc[i][jh * 4 + 2] + bs[jh * 4 + 2];
            v.w = acc[i][jh * 4 + 3] + bs[jh * 4 + 3];
            *(float4*)&C[(size_t)gm * 128 + jh * 64 + tx * 4] = v;
        }
    }
}

// ---- MP GEMM, BM=64, double-buffered, gathered A:
// C[e] = relu(inb[e] + (ma[b2a[e]]-bond[b2revb[e]]) @ wh^T), K=128
__global__ __launch_bounds__(256, 4) void gemm_mp(
    const float* __restrict__ ma, const float* __restrict__ bond,
    const int* __restrict__ b2a, const int* __restrict__ b2revb,
    const float* __restrict__ inb, const float* __restrict__ wh,
    float* __restrict__ C)
{
    __shared__ float As[2][16][68];
    __shared__ float Ws[2][16][132];
    __shared__ int ia[64], ir[64];
    const int tid = threadIdx.x;
    const int tx = tid & 15, ty = tid >> 4;
    const int row0 = blockIdx.x * 64;
    const int r  = tid >> 2;
    const int k4 = (tid & 3) * 4;
    if (tid < 64)       ia[tid]      = b2a[row0 + tid];
    else if (tid < 128) ir[tid - 64] = b2revb[row0 + tid - 64];
    __syncthreads();

    float4 px, py, pw[2];
    px = *(const float4*)(ma   + (size_t)ia[r] * 128 + k4);
    py = *(const float4*)(bond + (size_t)ir[r] * 128 + k4);
    pw[0] = *(const float4*)(wh + (size_t)r * 128 + k4);
    pw[1] = *(const float4*)(wh + (size_t)(r + 64) * 128 + k4);
    As[0][k4 + 0][r] = px.x - py.x; As[0][k4 + 1][r] = px.y - py.y;
    As[0][k4 + 2][r] = px.z - py.z; As[0][k4 + 3][r] = px.w - py.w;
#pragma unroll
    for (int c = 0; c < 2; ++c) {
        int rr = r + c * 64;
        Ws[0][k4 + 0][rr] = pw[c].x; Ws[0][k4 + 1][rr] = pw[c].y;
        Ws[0][k4 + 2][rr] = pw[c].z; Ws[0][k4 + 3][rr] = pw[c].w;
    }
    __syncthreads();

    float acc[4][8] = {};
#pragma unroll
    for (int s = 0; s < 8; ++s) {
        const int cur = s & 1;
        const bool more = (s < 7);
        if (more) {
            int kb = (s + 1) * 16 + k4;
            px = *(const float4*)(ma   + (size_t)ia[r] * 128 + kb);
            py = *(const float4*)(bond + (size_t)ir[r] * 128 + kb);
            pw[0] = *(const float4*)(wh + (size_t)r * 128 + kb);
            pw[1] = *(const float4*)(wh + (size_t)(r + 64) * 128 + kb);
        }
#pragma unroll
        for (int kk = 0; kk < 16; ++kk) {
            float4 a0 = *(const float4*)&As[cur][kk][ty * 4];
            float4 w0 = *(const float4*)&Ws[cur][kk][tx * 4];
            float4 w1 = *(const float4*)&Ws[cur][kk][64 + tx * 4];
            float a[4] = {a0.x, a0.y, a0.z, a0.w};
            float w[8] = {w0.x, w0.y, w0.z, w0.w, w1.x, w1.y, w1.z, w1.w};
#pragma unroll
            for (int i = 0; i < 4; ++i)
#pragma unroll
                for (int j = 0; j < 8; ++j)
                    acc[i][j] += a[i] * w[j];
        }
        if (more) {
            const int nxt = cur ^ 1;
            As[nxt][k4 + 0][r] = px.x - py.x; As[nxt][k4 + 1][r] = px.y - py.y;
            As[nxt][k4 + 2][r] = px.z - py.z; As[nxt][k4 + 3][r] = px.w - py.w;
#pragma unroll
            for (int c = 0; c < 2; ++c) {
                int rr = r + c * 64;
                Ws[nxt][k4 + 0][rr] = pw[c].x; Ws[nxt][k4 + 1][rr] = pw[c].y;
                Ws[nxt][k4 + 2][rr] = pw[c].z; Ws[nxt][k4 + 3][rr] = pw[c].w;
            }
            __syncthreads();
        }
    }
#pragma unroll
    for (int i = 0; i < 4; ++i) {
        int gm = row0 + ty * 4 + i;
#pragma unroll
        for (int jh = 0; jh < 2; ++jh) {
            int cc = jh * 64 + tx * 4;
            float4 o = *(const float4*)&inb[(size_t)gm * 128 + cc];
            float4 v;
            v.x = fmaxf(acc[i][jh * 4 + 0] + o.x, 0.f);
            v.y = fmaxf(acc[i][jh * 4 + 1] + o.y, 0.f);
            v.z = fmaxf(acc[i][jh * 4 + 2] + o.z, 0.f);
            v.w = fmaxf(acc[i][jh * 4 + 3] + o.w, 0.f);
            *(float4*)&C[(size_t)gm * 128 + cc] = v;
        }
    }
}

// ---------------- aggregation (float4, 8 nodes/block) ------------------------
__global__ __launch_bounds__(256) void agg_kernel(
    const float* __restrict__ bond, const int* __restrict__ a2b,
    float* __restrict__ ma, int N)
{
    int n = blockIdx.x * 8 + (threadIdx.x >> 5);
    if (n >= N) return;
    int d4 = (threadIdx.x & 31) * 4;
    const int* ix = a2b + (size_t)n * 6;
    float4 s = make_float4(0.f, 0.f, 0.f, 0.f);
    float4 mx = make_float4(-3.0e38f, -3.0e38f, -3.0e38f, -3.0e38f);
#pragma unroll
    for (int j = 0; j < 6; ++j) {
        float4 v = *(const float4*)(bond + (size_t)ix[j] * 128 + d4);
        s.x += v.x; s.y += v.y; s.z += v.z; s.w += v.w;
        mx.x = fmaxf(mx.x, v.x); mx.y = fmaxf(mx.y, v.y);
        mx.z = fmaxf(mx.z, v.z); mx.w = fmaxf(mx.w, v.w);
    }
    float* mp = ma + (size_t)n * 128 + d4;
    float4 o = *(const float4*)mp;
    o.x += s.x * mx.x; o.y += s.y * mx.y; o.z += s.z * mx.z; o.w += s.w * mx.w;
    *(float4*)mp = o;
}

// ---------------- CSR build over dst ----------------------------------------
__global__ void count_kernel(const int* __restrict__ dst, int* __restrict__ counts, int E)
{
    int e = blockIdx.x * 256 + threadIdx.x;
    if (e < E) atomicAdd(&counts[dst[e]], 1);
}

__global__ __launch_bounds__(1024) void scan_kernel(
    const int* __restrict__ counts, int* __restrict__ offsets, int N)
{
    __shared__ int sums[1024];
    int t = threadIdx.x;
    int chunk = (N + 1023) >> 10;
    int b = t * chunk;
    int e = b + chunk; if (e > N) e = N;
    int s = 0;
    for (int i = b; i < e; ++i) s += counts[i];
    sums[t] = s;
    __syncthreads();
    for (int off = 1; off < 1024; off <<= 1) {
        int v = (t >= off) ? sums[t - off] : 0;
        __syncthreads();
        sums[t] += v;
        __syncthreads();
    }
    int run = sums[t] - s;
    for (int i = b; i < e; ++i) { offsets[i] = run; run += counts[i]; }
    if (t == 1023) offsets[N] = sums[1023];
}

__global__ void fill_kernel(const int* __restrict__ dst, const int* __restrict__ offsets,
                            int* __restrict__ cursor, int* __restrict__ elist, int E)
{
    int e = blockIdx.x * 256 + threadIdx.x;
    if (e < E) {
        int d = dst[e];
        int pos = offsets[d] + atomicAdd(&cursor[d], 1);
        elist[pos] = e;
    }
}

// ---------------- attention pass 1: logits -> normalized alpha --------------
__global__ __launch_bounds__(256) void attn_pass1(
    const float* __restrict__ qh, const float* __restrict__ kh,
    const float* __restrict__ eh, const int* __restrict__ srcA,
    const int* __restrict__ offs, const int* __restrict__ elist,
    float* __restrict__ alpha, int N)
{
    int n = blockIdx.x * 4 + (threadIdx.x >> 6);
    if (n >= N) return;
    int l = threadIdx.x & 63;
    const float rs = 0.08838834764831845f;  // 1/sqrt(128)
    float2 q2 = ((const float2*)(qh + (size_t)n * 128))[l];
    int b = offs[n], en = offs[n + 1];
    float m = -3.0e38f, denom = 0.f;
    int ie = b;
    for (; ie + 2 <= en; ie += 2) {
        int e0 = elist[ie], e1 = elist[ie + 1];
        int s0 = srcA[e0], s1 = srcA[e1];
        float2 k0v = ((const float2*)(kh + (size_t)s0 * 128))[l];
        float2 e0v = ((const float2*)(eh + (size_t)e0 * 128))[l];
        float2 k1v = ((const float2*)(kh + (size_t)s1 * 128))[l];
        float2 e1v = ((const float2*)(eh + (size_t)e1 * 128))[l];
        float p0 = q2.x * (k0v.x + e0v.x) + q2.y * (k0v.y + e0v.y);
        float p1 = q2.x * (k1v.x + e1v.x) + q2.y * (k1v.y + e1v.y);
        p0 += __shfl_xor(p0, 1);  p1 += __shfl_xor(p1, 1);
        p0 += __shfl_xor(p0, 2);  p1 += __shfl_xor(p1, 2);
        p0 += __shfl_xor(p0, 4);  p1 += __shfl_xor(p1, 4);
        p0 += __shfl_xor(p0, 8);  p1 += __shfl_xor(p1, 8);
        p0 += __shfl_xor(p0, 16); p1 += __shfl_xor(p1, 16);
        p0 += __shfl_xor(p0, 32); p1 += __shfl_xor(p1, 32);
        float l0 = p0 * rs, l1 = p1 * rs;
        if (l == 0) { alpha[ie] = l0; alpha[ie + 1] = l1; }
        float mn = fmaxf(m, fmaxf(l0, l1));
        float sc = __expf(m - mn);
        denom = denom * sc + __expf(l0 - mn) + __expf(l1 - mn);
        m = mn;
    }
    if (ie < en) {
        int e0 = elist[ie];
        int s0 = srcA[e0];
        float2 k0v = ((const float2*)(kh + (size_t)s0 * 128))[l];
        float2 e0v = ((const float2*)(eh + (size_t)e0 * 128))[l];
        float p0 = q2.x * (k0v.x + e0v.x) + q2.y * (k0v.y + e0v.y);
        p0 += __shfl_xor(p0, 1);  p0 += __shfl_xor(p0, 2);
        p0 += __shfl_xor(p0, 4);  p0 += __shfl_xor(p0, 8);
        p0 += __shfl_xor(p0, 16); p0 += __shfl_xor(p0, 32);
        float l0 = p0 * rs;
        if (l == 0) alpha[ie] = l0;
        float mn = fmaxf(m, l0);
        denom = denom * __expf(m - mn) + __expf(l0 - mn);
        m = mn;
    }
    if (l == 0 && b < en) {
        float invd = 1.f / (denom + 1e-16f);
        for (int i = b; i < en; ++i)
            alpha[i] = __expf(alpha[i] - m) * invd;
    }
}

// ---------------- attention pass 2: outsum += 0.125 * alpha*(v[src]+eattr) --
__global__ __launch_bounds__(256) void attn_pass2(
    const float* __restrict__ vh, const float* __restrict__ eh,
    const int* __restrict__ srcA, const int* __restrict__ offs,
    const int* __restrict__ elist, const float* __restrict__ alpha,
    float* __restrict__ outsum, int N)
{
    int n = blockIdx.x * 4 + (threadIdx.x >> 6);
    if (n >= N) return;
    int l = threadIdx.x & 63;
    int b = offs[n], en = offs[n + 1];
    float a0 = 0.f, a1 = 0.f;
    int ie = b;
    for (; ie + 2 <= en; ie += 2) {
        int e0 = elist[ie], e1 = elist[ie + 1];
        int s0 = srcA[e0], s1 = srcA[e1];
        float al0 = alpha[ie], al1 = alpha[ie + 1];
        float2 v0 = ((const float2*)(vh + (size_t)s0 * 128))[l];
        float2 e0v = ((const float2*)(eh + (size_t)e0 * 128))[l];
        float2 v1 = ((const float2*)(vh + (size_t)s1 * 128))[l];
        float2 e1v = ((const float2*)(eh + (size_t)e1 * 128))[l];
        a0 += al0 * (v0.x + e0v.x) + al1 * (v1.x + e1v.x);
        a1 += al0 * (v0.y + e0v.y) + al1 * (v1.y + e1v.y);
    }
    if (ie < en) {
        int e0 = elist[ie];
        int s0 = srcA[e0];
        float al0 = alpha[ie];
        float2 v0 = ((const float2*)(vh + (size_t)s0 * 128))[l];
        float2 e0v = ((const float2*)(eh + (size_t)e0 * 128))[l];
        a0 += al0 * (v0.x + e0v.x);
        a1 += al0 * (v0.y + e0v.y);
    }
    float* op = outsum + (size_t)n * 128 + 2 * l;
    op[0] += 0.125f * a0;
    op[1] += 0.125f * a1;
}

// ---------------- Set2Set ----------------------------------------------------
__global__ void qv_kernel(const float* __restrict__ bih, const float* __restrict__ bhh,
                          float* __restrict__ qv)
{
    int t = threadIdx.x;  // 128 threads
    float gi = bih[t] + bhh[t];
    float gg = bih[256 + t] + bhh[256 + t];
    float go = bih[384 + t] + bhh[384 + t];
    float sig_i = 1.f / (1.f + __expf(-gi));
    float c = sig_i * tanhf(gg);
    float sig_o = 1.f / (1.f + __expf(-go));
    qv[t] = sig_o * tanhf(c);
}

__global__ __launch_bounds__(256) void s2s_kernel(
    const float* __restrict__ ah, const float* __restrict__ qv,
    const float* __restrict__ wo_w, const float* __restrict__ wo_b,
    float* __restrict__ out, int M)
{
    __shared__ float rsh[4][128];
    __shared__ float qsh[128];
    int wv = threadIdx.x >> 6, l = threadIdx.x & 63;
    if (threadIdx.x < 128) qsh[threadIdx.x] = qv[threadIdx.x];
    __syncthreads();
    int m = blockIdx.x * 4 + wv;
    bool active = (m < M);
    if (active) {
        const float* x = ah + (size_t)m * 20 * 128;
        float q0 = qsh[2 * l], q1 = qsh[2 * l + 1];
        float e[20]; float mx = -3.0e38f;
#pragma unroll
        for (int a = 0; a < 20; ++a) {
            float part = x[a * 128 + 2 * l] * q0 + x[a * 128 + 2 * l + 1] * q1;
            part += __shfl_xor(part, 1);  part += __shfl_xor(part, 2);
            part += __shfl_xor(part, 4);  part += __shfl_xor(part, 8);
            part += __shfl_xor(part, 16); part += __shfl_xor(part, 32);
            e[a] = part; mx = fmaxf(mx, part);
        }
        float sum = 0.f;
#pragma unroll
        for (int a = 0; a < 20; ++a) { e[a] = __expf(e[a] - mx); sum += e[a]; }
        float invs = 1.f / (sum + 1e-16f);
        float r0 = 0.f, r1 = 0.f;
#pragma unroll
        for (int a = 0; a < 20; ++a) {
            float w = e[a] * invs;
            r0 += w * x[a * 128 + 2 * l];
            r1 += w * x[a * 128 + 2 * l + 1];
        }
        rsh[wv][2 * l] = r0; rsh[wv][2 * l + 1] = r1;
    }
    __syncthreads();
    if (active) {
#pragma unroll
        for (int dd = 0; dd < 2; ++dd) {
            int d = 2 * l + dd;
            float acc = wo_b[d];
            const float* wr = wo_w + (size_t)d * 256;
            for (int j = 0; j < 128; ++j)
                acc += wr[j] * qsh[j] + wr[128 + j] * rsh[wv][j];
            out[(size_t)m * 128 + d] = acc;
        }
    }
}

// ---------------- launch -----------------------------------------------------
extern "C" void kernel_launch(void* const* d_in, const int* in_sizes, int n_in,
                              void* d_out, int out_size, void* d_ws, size_t ws_size,
                              hipStream_t stream)
{
    const int N = 60000, E = 120000, FA = 133, FB = 147;
    const float* f_atoms  = (const float*)d_in[0];
    const float* f_bonds  = (const float*)d_in[1];
    const float* wi_atom  = (const float*)d_in[2];
    const float* wi_bond  = (const float*)d_in[3];
    const float* wh[3]    = { (const float*)d_in[4], (const float*)d_in[5], (const float*)d_in[6] };
    const float* q_w      = (const float*)d_in[7];
    const float* q_b      = (const float*)d_in[8];
    const float* k_w      = (const float*)d_in[9];
    const float* k_b      = (const float*)d_in[10];
    const float* v_w      = (const float*)d_in[11];
    const float* v_b      = (const float*)d_in[12];
    const float* e_w      = (const float*)d_in[13];
    const float* skip_w   = (const float*)d_in[14];
    const float* skip_b   = (const float*)d_in[15];
    const float* lstm_bih = (const float*)d_in[18];
    const float* lstm_bhh = (const float*)d_in[19];
    const float* wo_w     = (const float*)d_in[20];
    const float* wo_b     = (const float*)d_in[21];
    const int* a2b    = (const int*)d_in[22];
    const int* b2a    = (const int*)d_in[23];
    const int* b2revb = (const int*)d_in[24];
    const int* bonds  = (const int*)d_in[25];
    const int* srcA = bonds;
    const int* dstA = bonds + E;

    // ---- workspace plan (~248 MB; ws_size is ~256 MiB — keep under) ----
    const size_t NB = (size_t)N * 128;
    const size_t EB = (size_t)E * 128;
    char* ws = (char*)d_ws;
    size_t off = 0;
    auto alloc = [&](size_t bytes) -> char* {
        char* p = ws + off; off += (bytes + 255) & ~255ULL; return p;
    };
    float* msg_atom = (float*)alloc(NB * 4);   // atoms, whole run
    float* B1       = (float*)alloc(EB * 4);   // input_bond -> [q|k] -> [v|k]
    float* B2       = (float*)alloc(EB * 4);   // bond ping (final msg_bond)
    float* B3       = (float*)alloc(EB * 4);   // bond pong -> eattr_h
    float* outsum   = (float*)alloc(NB * 4);   // skip-init, attn accum, = ah
    float* alpha    = (float*)alloc((size_t)E * 4);
    int* counts  = (int*)alloc((size_t)N * 2 * 4);   // counts | cursor contiguous
    int* cursor  = counts + N;
    int* offsets = (int*)alloc((size_t)(N + 1) * 4);
    int* elist   = (int*)alloc((size_t)E * 4);
    float* qvb   = (float*)alloc(128 * 4);

    if (off > ws_size) {
        long long n = out_size;
        sentinel_f32<<<(int)((n + 255) / 256), 256, 0, stream>>>((float*)d_out, n, 1.0e9f);
        return;
    }

    float* q_h = B1;            // [N,128]
    float* k_h = B1 + NB;       // [N,128]
    float* v_h = B1;            // [N,128] overwrites q after pass1
    float* e_h = B3;            // [E,128]

    const int gN128 = (N + 127) / 128;   // 469
    const int gE128 = (E + 127) / 128;   // 938
    const int gN64  = (N + 63) / 64;     // 938
    const int gE64  = E / 64;            // 1875 exact

    // 0. zero CSR state (graph-capture/replay-safe)
    zero_u32<<<(2 * N + 255) / 256, 256, 0, stream>>>((unsigned int*)counts, 2 * N);

    // 1. input projections (one merged launch, per-segment K)
    {
        GParams P{};
        P.s[0] = { f_atoms, wi_atom, nullptr, msg_atom, N, FA, gN128 };
        P.s[1] = { f_bonds, wi_bond, nullptr, B1,       E, FB, gN128 + gE128 };
        gemm_multi<true><<<gN128 + gE128, 256, 0, stream>>>(P, 2);
    }

    // 2. CSR over dst
    count_kernel<<<(E + 255) / 256, 256, 0, stream>>>(dstA, counts, E);
    scan_kernel<<<1, 1024, 0, stream>>>(counts, offsets, N);
    fill_kernel<<<(E + 255) / 256, 256, 0, stream>>>(dstA, offsets, cursor, elist, E);

    // 3. message passing: B1(input) -> B2 -> B3 -> B2 (gather-fused GEMM)
    const float* cur = B1;
    float* nxt[3] = { B2, B3, B2 };
    for (int it = 0; it < 3; ++it) {
        agg_kernel<<<(N + 7) / 8, 256, 0, stream>>>(cur, a2b, msg_atom, N);
        gemm_mp<<<gE64, 256, 0, stream>>>(
            msg_atom, cur, b2a, b2revb, B1, wh[it], nxt[it]);
        cur = nxt[it];
    }
    // final message_bond = B2; B1, B3 now dead

    // 4./5. TransformerConv per head; skip-GEMM rides in head 0's launch
    for (int h = 0; h < 8; ++h) {
        const size_t w_off = (size_t)h * 128 * 128;
        GParams P{};
        P.s[0] = { B2,       e_w + w_off, nullptr,        e_h, E, 128, gE128 };
        P.s[1] = { msg_atom, q_w + w_off, q_b + h * 128,  q_h, N, 128, gE128 + gN128 };
        P.s[2] = { msg_atom, k_w + w_off, k_b + h * 128,  k_h, N, 128, gE128 + 2 * gN128 };
        int nseg = 3, nblk = gE128 + 2 * gN128;
        if (h == 0) {
            P.s[3] = { msg_atom, skip_w, skip_b, outsum, N, 128, gE128 + 3 * gN128 };
            nseg = 4; nblk += gN128;
        }
        gemm_multi<false><<<nblk, 256, 0, stream>>>(P, nseg);
        attn_pass1<<<(N + 3) / 4, 256, 0, stream>>>(
            q_h, k_h, e_h, srcA, offsets, elist, alpha, N);
        gemm64<<<gN64, 256, 0, stream>>>(msg_atom, v_w + w_off, v_b + h * 128, v_h, N);
        attn_pass2<<<(N + 3) / 4, 256, 0, stream>>>(
            v_h, e_h, srcA, offsets, elist, alpha, outsum, N);
    }

    // 6. Set2Set + output projection (outsum == atom_hiddens)
    qv_kernel<<<1, 128, 0, stream>>>(lstm_bih, lstm_bhh, qvb);
    const int M = N / 20;  // 3000 molecules
    s2s_kernel<<<(M + 3) / 4, 256, 0, stream>>>(outsum, qvb, wo_w, wo_b, (float*)d_out, M);
}

// Round 8
// 20548.715 us; speedup vs baseline: 1.8135x; 1.8135x over previous
//
#include <hip/hip_runtime.h>
#include <hip/hip_bf16.h>

// ---------------- utility kernels ------------------------------------------
__global__ void zero_u32(unsigned int* __restrict__ p, long long n)
{
    long long i = (long long)blockIdx.x * 256 + threadIdx.x;
    if (i < n) p[i] = 0u;
}

__global__ void sentinel_f32(float* __restrict__ p, long long n, float v)
{
    long long i = (long long)blockIdx.x * 256 + threadIdx.x;
    if (i < n) p[i] = v;
}

__device__ __forceinline__ float4 load_f4_guard(const float* base, int gm, int M, int K, int kb)
{
    float4 v = make_float4(0.f, 0.f, 0.f, 0.f);
    if (gm < M) {
        const float* p = base + (size_t)gm * K + kb;
        if (kb + 4 <= K) v = *(const float4*)p;
        else {
            if (kb     < K) v.x = p[0];
            if (kb + 1 < K) v.y = p[1];
            if (kb + 2 < K) v.z = p[2];
            if (kb + 3 < K) v.w = p[3];
        }
    }
    return v;
}

// ---------------- multi-segment GEMM, double-buffered ------------------------
// C[M,128] = act(A[M,K] @ W[128,K]^T + bias?), up to 4 independent segments.
// 128x128 tile, BK=16, 8x8/thread, 2-deep LDS pipeline (1 barrier / K-step).
// NOTE: no 2nd __launch_bounds__ arg — R7 proved it caps VGPR at 64 and spills.
struct GSeg {
    const float* A; const float* W; const float* bias; float* C;
    int M; int K; int bend;   // bend = exclusive block-id end of this segment
};
struct GParams { GSeg s[4]; };

template<bool RELU>
__global__ __launch_bounds__(256) void gemm_multi(GParams P, int nseg)
{
    __shared__ float As[2][16][132];
    __shared__ float Ws[2][16][132];
    const int b = blockIdx.x;
    int si = 0, bbeg = 0;
    while (si + 1 < nseg && b >= P.s[si].bend) { bbeg = P.s[si].bend; ++si; }
    const GSeg S = P.s[si];
    const int tid = threadIdx.x;
    const int tx = tid & 15, ty = tid >> 4;
    const int row0 = (b - bbeg) * 128;
    const int r  = tid >> 2;          // 0..63
    const int k4 = (tid & 3) * 4;     // 0,4,8,12
    const int nsteps = (S.K + 15) >> 4;

    float4 pa[2], pw[2];
    // prefetch step 0
#pragma unroll
    for (int c = 0; c < 2; ++c) {
        int rr = r + c * 64;
        pa[c] = load_f4_guard(S.A, row0 + rr, S.M, S.K, k4);
        pw[c] = load_f4_guard(S.W, rr, 128, S.K, k4);
    }
#pragma unroll
    for (int c = 0; c < 2; ++c) {
        int rr = r + c * 64;
        As[0][k4 + 0][rr] = pa[c].x; As[0][k4 + 1][rr] = pa[c].y;
        As[0][k4 + 2][rr] = pa[c].z; As[0][k4 + 3][rr] = pa[c].w;
        Ws[0][k4 + 0][rr] = pw[c].x; Ws[0][k4 + 1][rr] = pw[c].y;
        Ws[0][k4 + 2][rr] = pw[c].z; Ws[0][k4 + 3][rr] = pw[c].w;
    }
    __syncthreads();

    float acc[8][8] = {};
    for (int s = 0; s < nsteps; ++s) {
        const int cur = s & 1;
        const bool more = (s + 1 < nsteps);
        if (more) {
            int kb = (s + 1) * 16 + k4;
#pragma unroll
            for (int c = 0; c < 2; ++c) {
                int rr = r + c * 64;
                pa[c] = load_f4_guard(S.A, row0 + rr, S.M, S.K, kb);
                pw[c] = load_f4_guard(S.W, rr, 128, S.K, kb);
            }
        }
#pragma unroll
        for (int kk = 0; kk < 16; ++kk) {
            float4 a0 = *(const float4*)&As[cur][kk][ty * 4];
            float4 a1 = *(const float4*)&As[cur][kk][64 + ty * 4];
            float4 w0 = *(const float4*)&Ws[cur][kk][tx * 4];
            float4 w1 = *(const float4*)&Ws[cur][kk][64 + tx * 4];
            float a[8] = {a0.x, a0.y, a0.z, a0.w, a1.x, a1.y, a1.z, a1.w};
            float w[8] = {w0.x, w0.y, w0.z, w0.w, w1.x, w1.y, w1.z, w1.w};
#pragma unroll
            for (int i = 0; i < 8; ++i)
#pragma unroll
                for (int j = 0; j < 8; ++j)
                    acc[i][j] += a[i] * w[j];
        }
        if (more) {
            const int nxt = cur ^ 1;
#pragma unroll
            for (int c = 0; c < 2; ++c) {
                int rr = r + c * 64;
                As[nxt][k4 + 0][rr] = pa[c].x; As[nxt][k4 + 1][rr] = pa[c].y;
                As[nxt][k4 + 2][rr] = pa[c].z; As[nxt][k4 + 3][rr] = pa[c].w;
                Ws[nxt][k4 + 0][rr] = pw[c].x; Ws[nxt][k4 + 1][rr] = pw[c].y;
                Ws[nxt][k4 + 2][rr] = pw[c].z; Ws[nxt][k4 + 3][rr] = pw[c].w;
            }
            __syncthreads();
        }
    }
    float bs[8];
    if (S.bias) {
#pragma unroll
        for (int j = 0; j < 4; ++j) {
            bs[j]     = S.bias[tx * 4 + j];
            bs[j + 4] = S.bias[64 + tx * 4 + j];
        }
    } else {
#pragma unroll
        for (int j = 0; j < 8; ++j) bs[j] = 0.f;
    }
#pragma unroll
    for (int i = 0; i < 8; ++i) {
        int rr = (i < 4) ? (ty * 4 + i) : (64 + ty * 4 + i - 4);
        int gm = row0 + rr;
        if (gm >= S.M) continue;
#pragma unroll
        for (int jh = 0; jh < 2; ++jh) {
            float4 v;
            v.x = acc[i][jh * 4 + 0] + bs[jh * 4 + 0];
            v.y = acc[i][jh * 4 + 1] + bs[jh * 4 + 1];
            v.z = acc[i][jh * 4 + 2] + bs[jh * 4 + 2];
            v.w = acc[i][jh * 4 + 3] + bs[jh * 4 + 3];
            if (RELU) {
                v.x = fmaxf(v.x, 0.f); v.y = fmaxf(v.y, 0.f);
                v.z = fmaxf(v.z, 0.f); v.w = fmaxf(v.w, 0.f);
            }
            *(float4*)&S.C[(size_t)gm * 128 + jh * 64 + tx * 4] = v;
        }
    }
}

// ---------------- BM=64 GEMM, double-buffered, K=128 fixed -------------------
__global__ __launch_bounds__(256) void gemm64(
    const float* __restrict__ A, const float* __restrict__ W,
    const float* __restrict__ bias, float* __restrict__ C, int M)
{
    __shared__ float As[2][16][68];
    __shared__ float Ws[2][16][132];
    const int tid = threadIdx.x;
    const int tx = tid & 15, ty = tid >> 4;
    const int row0 = blockIdx.x * 64;
    const int r  = tid >> 2;
    const int k4 = (tid & 3) * 4;

    float4 pa, pw[2];
    {
        int gm = row0 + r;
        pa = make_float4(0.f, 0.f, 0.f, 0.f);
        if (gm < M) pa = *(const float4*)(A + (size_t)gm * 128 + k4);
        pw[0] = *(const float4*)(W + (size_t)r * 128 + k4);
        pw[1] = *(const float4*)(W + (size_t)(r + 64) * 128 + k4);
    }
    As[0][k4 + 0][r] = pa.x; As[0][k4 + 1][r] = pa.y;
    As[0][k4 + 2][r] = pa.z; As[0][k4 + 3][r] = pa.w;
#pragma unroll
    for (int c = 0; c < 2; ++c) {
        int rr = r + c * 64;
        Ws[0][k4 + 0][rr] = pw[c].x; Ws[0][k4 + 1][rr] = pw[c].y;
        Ws[0][k4 + 2][rr] = pw[c].z; Ws[0][k4 + 3][rr] = pw[c].w;
    }
    __syncthreads();

    float acc[4][8] = {};
#pragma unroll
    for (int s = 0; s < 8; ++s) {
        const int cur = s & 1;
        const bool more = (s < 7);
        if (more) {
            int kb = (s + 1) * 16 + k4;
            int gm = row0 + r;
            pa = make_float4(0.f, 0.f, 0.f, 0.f);
            if (gm < M) pa = *(const float4*)(A + (size_t)gm * 128 + kb);
            pw[0] = *(const float4*)(W + (size_t)r * 128 + kb);
            pw[1] = *(const float4*)(W + (size_t)(r + 64) * 128 + kb);
        }
#pragma unroll
        for (int kk = 0; kk < 16; ++kk) {
            float4 a0 = *(const float4*)&As[cur][kk][ty * 4];
            float4 w0 = *(const float4*)&Ws[cur][kk][tx * 4];
            float4 w1 = *(const float4*)&Ws[cur][kk][64 + tx * 4];
            float a[4] = {a0.x, a0.y, a0.z, a0.w};
            float w[8] = {w0.x, w0.y, w0.z, w0.w, w1.x, w1.y, w1.z, w1.w};
#pragma unroll
            for (int i = 0; i < 4; ++i)
#pragma unroll
                for (int j = 0; j < 8; ++j)
                    acc[i][j] += a[i] * w[j];
        }
        if (more) {
            const int nxt = cur ^ 1;
            As[nxt][k4 + 0][r] = pa.x; As[nxt][k4 + 1][r] = pa.y;
            As[nxt][k4 + 2][r] = pa.z; As[nxt][k4 + 3][r] = pa.w;
#pragma unroll
            for (int c = 0; c < 2; ++c) {
                int rr = r + c * 64;
                Ws[nxt][k4 + 0][rr] = pw[c].x; Ws[nxt][k4 + 1][rr] = pw[c].y;
                Ws[nxt][k4 + 2][rr] = pw[c].z; Ws[nxt][k4 + 3][rr] = pw[c].w;
            }
            __syncthreads();
        }
    }
    float bs[8];
#pragma unroll
    for (int j = 0; j < 4; ++j) {
        bs[j]     = bias ? bias[tx * 4 + j] : 0.f;
        bs[j + 4] = bias ? bias[64 + tx * 4 + j] : 0.f;
    }
#pragma unroll
    for (int i = 0; i < 4; ++i) {
        int gm = row0 + ty * 4 + i;
        if (gm >= M) continue;
#pragma unroll
        for (int jh = 0; jh < 2; ++jh) {
            float4 v;
            v.x = acc[i][jh * 4 + 0] + bs[jh * 4 + 0];
            v.y = acc[i][jh * 4 + 1] + bs[jh * 4 + 1];
            v.z = acc[i][jh * 4 + 2] + bs[jh * 4 + 2];
            v.w = acc[i][jh * 4 + 3] + bs[jh * 4 + 3];
            *(float4*)&C[(size_t)gm * 128 + jh * 64 + tx * 4] = v;
        }
    }
}

// ---- MP GEMM, BM=64, double-buffered, gathered A:
// C[e] = relu(inb[e] + (ma[b2a[e]]-bond[b2revb[e]]) @ wh^T), K=128
__global__ __launch_bounds__(256) void gemm_mp(
    const float* __restrict__ ma, const float* __restrict__ bond,
    const int* __restrict__ b2a, const int* __restrict__ b2revb,
    const float* __restrict__ inb, const float* __restrict__ wh,
    float* __restrict__ C)
{
    __shared__ float As[2][16][68];
    __shared__ float Ws[2][16][132];
    __shared__ int ia[64], ir[64];
    const int tid = threadIdx.x;
    const int tx = tid & 15, ty = tid >> 4;
    const int row0 = blockIdx.x * 64;
    const int r  = tid >> 2;
    const int k4 = (tid & 3) * 4;
    if (tid < 64)       ia[tid]      = b2a[row0 + tid];
    else if (tid < 128) ir[tid - 64] = b2revb[row0 + tid - 64];
    __syncthreads();

    float4 px, py, pw[2];
    px = *(const float4*)(ma   + (size_t)ia[r] * 128 + k4);
    py = *(const float4*)(bond + (size_t)ir[r] * 128 + k4);
    pw[0] = *(const float4*)(wh + (size_t)r * 128 + k4);
    pw[1] = *(const float4*)(wh + (size_t)(r + 64) * 128 + k4);
    As[0][k4 + 0][r] = px.x - py.x; As[0][k4 + 1][r] = px.y - py.y;
    As[0][k4 + 2][r] = px.z - py.z; As[0][k4 + 3][r] = px.w - py.w;
#pragma unroll
    for (int c = 0; c < 2; ++c) {
        int rr = r + c * 64;
        Ws[0][k4 + 0][rr] = pw[c].x; Ws[0][k4 + 1][rr] = pw[c].y;
        Ws[0][k4 + 2][rr] = pw[c].z; Ws[0][k4 + 3][rr] = pw[c].w;
    }
    __syncthreads();

    float acc[4][8] = {};
#pragma unroll
    for (int s = 0; s < 8; ++s) {
        const int cur = s & 1;
        const bool more = (s < 7);
        if (more) {
            int kb = (s + 1) * 16 + k4;
            px = *(const float4*)(ma   + (size_t)ia[r] * 128 + kb);
            py = *(const float4*)(bond + (size_t)ir[r] * 128 + kb);
            pw[0] = *(const float4*)(wh + (size_t)r * 128 + kb);
            pw[1] = *(const float4*)(wh + (size_t)(r + 64) * 128 + kb);
        }
#pragma unroll
        for (int kk = 0; kk < 16; ++kk) {
            float4 a0 = *(const float4*)&As[cur][kk][ty * 4];
            float4 w0 = *(const float4*)&Ws[cur][kk][tx * 4];
            float4 w1 = *(const float4*)&Ws[cur][kk][64 + tx * 4];
            float a[4] = {a0.x, a0.y, a0.z, a0.w};
            float w[8] = {w0.x, w0.y, w0.z, w0.w, w1.x, w1.y, w1.z, w1.w};
#pragma unroll
            for (int i = 0; i < 4; ++i)
#pragma unroll
                for (int j = 0; j < 8; ++j)
                    acc[i][j] += a[i] * w[j];
        }
        if (more) {
            const int nxt = cur ^ 1;
            As[nxt][k4 + 0][r] = px.x - py.x; As[nxt][k4 + 1][r] = px.y - py.y;
            As[nxt][k4 + 2][r] = px.z - py.z; As[nxt][k4 + 3][r] = px.w - py.w;
#pragma unroll
            for (int c = 0; c < 2; ++c) {
                int rr = r + c * 64;
                Ws[nxt][k4 + 0][rr] = pw[c].x; Ws[nxt][k4 + 1][rr] = pw[c].y;
                Ws[nxt][k4 + 2][rr] = pw[c].z; Ws[nxt][k4 + 3][rr] = pw[c].w;
            }
            __syncthreads();
        }
    }
#pragma unroll
    for (int i = 0; i < 4; ++i) {
        int gm = row0 + ty * 4 + i;
#pragma unroll
        for (int jh = 0; jh < 2; ++jh) {
            int cc = jh * 64 + tx * 4;
            float4 o = *(const float4*)&inb[(size_t)gm * 128 + cc];
            float4 v;
            v.x = fmaxf(acc[i][jh * 4 + 0] + o.x, 0.f);
            v.y = fmaxf(acc[i][jh * 4 + 1] + o.y, 0.f);
            v.z = fmaxf(acc[i][jh * 4 + 2] + o.z, 0.f);
            v.w = fmaxf(acc[i][jh * 4 + 3] + o.w, 0.f);
            *(float4*)&C[(size_t)gm * 128 + cc] = v;
        }
    }
}

// ---------------- aggregation (float4, 8 nodes/block) ------------------------
__global__ __launch_bounds__(256) void agg_kernel(
    const float* __restrict__ bond, const int* __restrict__ a2b,
    float* __restrict__ ma, int N)
{
    int n = blockIdx.x * 8 + (threadIdx.x >> 5);
    if (n >= N) return;
    int d4 = (threadIdx.x & 31) * 4;
    const int* ix = a2b + (size_t)n * 6;
    float4 s = make_float4(0.f, 0.f, 0.f, 0.f);
    float4 mx = make_float4(-3.0e38f, -3.0e38f, -3.0e38f, -3.0e38f);
#pragma unroll
    for (int j = 0; j < 6; ++j) {
        float4 v = *(const float4*)(bond + (size_t)ix[j] * 128 + d4);
        s.x += v.x; s.y += v.y; s.z += v.z; s.w += v.w;
        mx.x = fmaxf(mx.x, v.x); mx.y = fmaxf(mx.y, v.y);
        mx.z = fmaxf(mx.z, v.z); mx.w = fmaxf(mx.w, v.w);
    }
    float* mp = ma + (size_t)n * 128 + d4;
    float4 o = *(const float4*)mp;
    o.x += s.x * mx.x; o.y += s.y * mx.y; o.z += s.z * mx.z; o.w += s.w * mx.w;
    *(float4*)mp = o;
}

// ---------------- CSR build over dst ----------------------------------------
__global__ void count_kernel(const int* __restrict__ dst, int* __restrict__ counts, int E)
{
    int e = blockIdx.x * 256 + threadIdx.x;
    if (e < E) atomicAdd(&counts[dst[e]], 1);
}

__global__ __launch_bounds__(1024) void scan_kernel(
    const int* __restrict__ counts, int* __restrict__ offsets, int N)
{
    __shared__ int sums[1024];
    int t = threadIdx.x;
    int chunk = (N + 1023) >> 10;
    int b = t * chunk;
    int e = b + chunk; if (e > N) e = N;
    int s = 0;
    for (int i = b; i < e; ++i) s += counts[i];
    sums[t] = s;
    __syncthreads();
    for (int off = 1; off < 1024; off <<= 1) {
        int v = (t >= off) ? sums[t - off] : 0;
        __syncthreads();
        sums[t] += v;
        __syncthreads();
    }
    int run = sums[t] - s;
    for (int i = b; i < e; ++i) { offsets[i] = run; run += counts[i]; }
    if (t == 1023) offsets[N] = sums[1023];
}

__global__ void fill_kernel(const int* __restrict__ dst, const int* __restrict__ offsets,
                            int* __restrict__ cursor, int* __restrict__ elist, int E)
{
    int e = blockIdx.x * 256 + threadIdx.x;
    if (e < E) {
        int d = dst[e];
        int pos = offsets[d] + atomicAdd(&cursor[d], 1);
        elist[pos] = e;
    }
}

// ---------------- attention pass 1: logits -> normalized alpha --------------
__global__ __launch_bounds__(256) void attn_pass1(
    const float* __restrict__ qh, const float* __restrict__ kh,
    const float* __restrict__ eh, const int* __restrict__ srcA,
    const int* __restrict__ offs, const int* __restrict__ elist,
    float* __restrict__ alpha, int N)
{
    int n = blockIdx.x * 4 + (threadIdx.x >> 6);
    if (n >= N) return;
    int l = threadIdx.x & 63;
    const float rs = 0.08838834764831845f;  // 1/sqrt(128)
    float2 q2 = ((const float2*)(qh + (size_t)n * 128))[l];
    int b = offs[n], en = offs[n + 1];
    float m = -3.0e38f, denom = 0.f;
    int ie = b;
    for (; ie + 2 <= en; ie += 2) {
        int e0 = elist[ie], e1 = elist[ie + 1];
        int s0 = srcA[e0], s1 = srcA[e1];
        float2 k0v = ((const float2*)(kh + (size_t)s0 * 128))[l];
        float2 e0v = ((const float2*)(eh + (size_t)e0 * 128))[l];
        float2 k1v = ((const float2*)(kh + (size_t)s1 * 128))[l];
        float2 e1v = ((const float2*)(eh + (size_t)e1 * 128))[l];
        float p0 = q2.x * (k0v.x + e0v.x) + q2.y * (k0v.y + e0v.y);
        float p1 = q2.x * (k1v.x + e1v.x) + q2.y * (k1v.y + e1v.y);
        p0 += __shfl_xor(p0, 1);  p1 += __shfl_xor(p1, 1);
        p0 += __shfl_xor(p0, 2);  p1 += __shfl_xor(p1, 2);
        p0 += __shfl_xor(p0, 4);  p1 += __shfl_xor(p1, 4);
        p0 += __shfl_xor(p0, 8);  p1 += __shfl_xor(p1, 8);
        p0 += __shfl_xor(p0, 16); p1 += __shfl_xor(p1, 16);
        p0 += __shfl_xor(p0, 32); p1 += __shfl_xor(p1, 32);
        float l0 = p0 * rs, l1 = p1 * rs;
        if (l == 0) { alpha[ie] = l0; alpha[ie + 1] = l1; }
        float mn = fmaxf(m, fmaxf(l0, l1));
        float sc = __expf(m - mn);
        denom = denom * sc + __expf(l0 - mn) + __expf(l1 - mn);
        m = mn;
    }
    if (ie < en) {
        int e0 = elist[ie];
        int s0 = srcA[e0];
        float2 k0v = ((const float2*)(kh + (size_t)s0 * 128))[l];
        float2 e0v = ((const float2*)(eh + (size_t)e0 * 128))[l];
        float p0 = q2.x * (k0v.x + e0v.x) + q2.y * (k0v.y + e0v.y);
        p0 += __shfl_xor(p0, 1);  p0 += __shfl_xor(p0, 2);
        p0 += __shfl_xor(p0, 4);  p0 += __shfl_xor(p0, 8);
        p0 += __shfl_xor(p0, 16); p0 += __shfl_xor(p0, 32);
        float l0 = p0 * rs;
        if (l == 0) alpha[ie] = l0;
        float mn = fmaxf(m, l0);
        denom = denom * __expf(m - mn) + __expf(l0 - mn);
        m = mn;
    }
    if (l == 0 && b < en) {
        float invd = 1.f / (denom + 1e-16f);
        for (int i = b; i < en; ++i)
            alpha[i] = __expf(alpha[i] - m) * invd;
    }
}

// ---------------- attention pass 2: outsum += 0.125 * alpha*(v[src]+eattr) --
__global__ __launch_bounds__(256) void attn_pass2(
    const float* __restrict__ vh, const float* __restrict__ eh,
    const int* __restrict__ srcA, const int* __restrict__ offs,
    const int* __restrict__ elist, const float* __restrict__ alpha,
    float* __restrict__ outsum, int N)
{
    int n = blockIdx.x * 4 + (threadIdx.x >> 6);
    if (n >= N) return;
    int l = threadIdx.x & 63;
    int b = offs[n], en = offs[n + 1];
    float a0 = 0.f, a1 = 0.f;
    int ie = b;
    for (; ie + 2 <= en; ie += 2) {
        int e0 = elist[ie], e1 = elist[ie + 1];
        int s0 = srcA[e0], s1 = srcA[e1];
        float al0 = alpha[ie], al1 = alpha[ie + 1];
        float2 v0 = ((const float2*)(vh + (size_t)s0 * 128))[l];
        float2 e0v = ((const float2*)(eh + (size_t)e0 * 128))[l];
        float2 v1 = ((const float2*)(vh + (size_t)s1 * 128))[l];
        float2 e1v = ((const float2*)(eh + (size_t)e1 * 128))[l];
        a0 += al0 * (v0.x + e0v.x) + al1 * (v1.x + e1v.x);
        a1 += al0 * (v0.y + e0v.y) + al1 * (v1.y + e1v.y);
    }
    if (ie < en) {
        int e0 = elist[ie];
        int s0 = srcA[e0];
        float al0 = alpha[ie];
        float2 v0 = ((const float2*)(vh + (size_t)s0 * 128))[l];
        float2 e0v = ((const float2*)(eh + (size_t)e0 * 128))[l];
        a0 += al0 * (v0.x + e0v.x);
        a1 += al0 * (v0.y + e0v.y);
    }
    float* op = outsum + (size_t)n * 128 + 2 * l;
    op[0] += 0.125f * a0;
    op[1] += 0.125f * a1;
}

// ---------------- Set2Set ----------------------------------------------------
__global__ void qv_kernel(const float* __restrict__ bih, const float* __restrict__ bhh,
                          float* __restrict__ qv)
{
    int t = threadIdx.x;  // 128 threads
    float gi = bih[t] + bhh[t];
    float gg = bih[256 + t] + bhh[256 + t];
    float go = bih[384 + t] + bhh[384 + t];
    float sig_i = 1.f / (1.f + __expf(-gi));
    float c = sig_i * tanhf(gg);
    float sig_o = 1.f / (1.f + __expf(-go));
    qv[t] = sig_o * tanhf(c);
}

__global__ __launch_bounds__(256) void s2s_kernel(
    const float* __restrict__ ah, const float* __restrict__ qv,
    const float* __restrict__ wo_w, const float* __restrict__ wo_b,
    float* __restrict__ out, int M)
{
    __shared__ float rsh[4][128];
    __shared__ float qsh[128];
    int wv = threadIdx.x >> 6, l = threadIdx.x & 63;
    if (threadIdx.x < 128) qsh[threadIdx.x] = qv[threadIdx.x];
    __syncthreads();
    int m = blockIdx.x * 4 + wv;
    bool active = (m < M);
    if (active) {
        const float* x = ah + (size_t)m * 20 * 128;
        float q0 = qsh[2 * l], q1 = qsh[2 * l + 1];
        float e[20]; float mx = -3.0e38f;
#pragma unroll
        for (int a = 0; a < 20; ++a) {
            float part = x[a * 128 + 2 * l] * q0 + x[a * 128 + 2 * l + 1] * q1;
            part += __shfl_xor(part, 1);  part += __shfl_xor(part, 2);
            part += __shfl_xor(part, 4);  part += __shfl_xor(part, 8);
            part += __shfl_xor(part, 16); part += __shfl_xor(part, 32);
            e[a] = part; mx = fmaxf(mx, part);
        }
        float sum = 0.f;
#pragma unroll
        for (int a = 0; a < 20; ++a) { e[a] = __expf(e[a] - mx); sum += e[a]; }
        float invs = 1.f / (sum + 1e-16f);
        float r0 = 0.f, r1 = 0.f;
#pragma unroll
        for (int a = 0; a < 20; ++a) {
            float w = e[a] * invs;
            r0 += w * x[a * 128 + 2 * l];
            r1 += w * x[a * 128 + 2 * l + 1];
        }
        rsh[wv][2 * l] = r0; rsh[wv][2 * l + 1] = r1;
    }
    __syncthreads();
    if (active) {
#pragma unroll
        for (int dd = 0; dd < 2; ++dd) {
            int d = 2 * l + dd;
            float acc = wo_b[d];
            const float* wr = wo_w + (size_t)d * 256;
            for (int j = 0; j < 128; ++j)
                acc += wr[j] * qsh[j] + wr[128 + j] * rsh[wv][j];
            out[(size_t)m * 128 + d] = acc;
        }
    }
}

// ---------------- launch -----------------------------------------------------
extern "C" void kernel_launch(void* const* d_in, const int* in_sizes, int n_in,
                              void* d_out, int out_size, void* d_ws, size_t ws_size,
                              hipStream_t stream)
{
    const int N = 60000, E = 120000, FA = 133, FB = 147;
    const float* f_atoms  = (const float*)d_in[0];
    const float* f_bonds  = (const float*)d_in[1];
    const float* wi_atom  = (const float*)d_in[2];
    const float* wi_bond  = (const float*)d_in[3];
    const float* wh[3]    = { (const float*)d_in[4], (const float*)d_in[5], (const float*)d_in[6] };
    const float* q_w      = (const float*)d_in[7];
    const float* q_b      = (const float*)d_in[8];
    const float* k_w      = (const float*)d_in[9];
    const float* k_b      = (const float*)d_in[10];
    const float* v_w      = (const float*)d_in[11];
    const float* v_b      = (const float*)d_in[12];
    const float* e_w      = (const float*)d_in[13];
    const float* skip_w   = (const float*)d_in[14];
    const float* skip_b   = (const float*)d_in[15];
    const float* lstm_bih = (const float*)d_in[18];
    const float* lstm_bhh = (const float*)d_in[19];
    const float* wo_w     = (const float*)d_in[20];
    const float* wo_b     = (const float*)d_in[21];
    const int* a2b    = (const int*)d_in[22];
    const int* b2a    = (const int*)d_in[23];
    const int* b2revb = (const int*)d_in[24];
    const int* bonds  = (const int*)d_in[25];
    const int* srcA = bonds;
    const int* dstA = bonds + E;

    // ---- workspace plan (~248 MB; ws_size is ~256 MiB — keep under) ----
    const size_t NB = (size_t)N * 128;
    const size_t EB = (size_t)E * 128;
    char* ws = (char*)d_ws;
    size_t off = 0;
    auto alloc = [&](size_t bytes) -> char* {
        char* p = ws + off; off += (bytes + 255) & ~255ULL; return p;
    };
    float* msg_atom = (float*)alloc(NB * 4);   // atoms, whole run
    float* B1       = (float*)alloc(EB * 4);   // input_bond -> [q|k] -> [v|k]
    float* B2       = (float*)alloc(EB * 4);   // bond ping (final msg_bond)
    float* B3       = (float*)alloc(EB * 4);   // bond pong -> eattr_h
    float* outsum   = (float*)alloc(NB * 4);   // skip-init, attn accum, = ah
    float* alpha    = (float*)alloc((size_t)E * 4);
    int* counts  = (int*)alloc((size_t)N * 2 * 4);   // counts | cursor contiguous
    int* cursor  = counts + N;
    int* offsets = (int*)alloc((size_t)(N + 1) * 4);
    int* elist   = (int*)alloc((size_t)E * 4);
    float* qvb   = (float*)alloc(128 * 4);

    if (off > ws_size) {
        long long n = out_size;
        sentinel_f32<<<(int)((n + 255) / 256), 256, 0, stream>>>((float*)d_out, n, 1.0e9f);
        return;
    }

    float* q_h = B1;            // [N,128]
    float* k_h = B1 + NB;       // [N,128]
    float* v_h = B1;            // [N,128] overwrites q after pass1
    float* e_h = B3;            // [E,128]

    const int gN128 = (N + 127) / 128;   // 469
    const int gE128 = (E + 127) / 128;   // 938
    const int gN64  = (N + 63) / 64;     // 938
    const int gE64  = E / 64;            // 1875 exact

    // 0. zero CSR state (graph-capture/replay-safe)
    zero_u32<<<(2 * N + 255) / 256, 256, 0, stream>>>((unsigned int*)counts, 2 * N);

    // 1. input projections (one merged launch, per-segment K)
    {
        GParams P{};
        P.s[0] = { f_atoms, wi_atom, nullptr, msg_atom, N, FA, gN128 };
        P.s[1] = { f_bonds, wi_bond, nullptr, B1,       E, FB, gN128 + gE128 };
        gemm_multi<true><<<gN128 + gE128, 256, 0, stream>>>(P, 2);
    }

    // 2. CSR over dst
    count_kernel<<<(E + 255) / 256, 256, 0, stream>>>(dstA, counts, E);
    scan_kernel<<<1, 1024, 0, stream>>>(counts, offsets, N);
    fill_kernel<<<(E + 255) / 256, 256, 0, stream>>>(dstA, offsets, cursor, elist, E);

    // 3. message passing: B1(input) -> B2 -> B3 -> B2 (gather-fused GEMM)
    const float* cur = B1;
    float* nxt[3] = { B2, B3, B2 };
    for (int it = 0; it < 3; ++it) {
        agg_kernel<<<(N + 7) / 8, 256, 0, stream>>>(cur, a2b, msg_atom, N);
        gemm_mp<<<gE64, 256, 0, stream>>>(
            msg_atom, cur, b2a, b2revb, B1, wh[it], nxt[it]);
        cur = nxt[it];
    }
    // final message_bond = B2; B1, B3 now dead

    // 4./5. TransformerConv per head; skip-GEMM rides in head 0's launch
    for (int h = 0; h < 8; ++h) {
        const size_t w_off = (size_t)h * 128 * 128;
        GParams P{};
        P.s[0] = { B2,       e_w + w_off, nullptr,        e_h, E, 128, gE128 };
        P.s[1] = { msg_atom, q_w + w_off, q_b + h * 128,  q_h, N, 128, gE128 + gN128 };
        P.s[2] = { msg_atom, k_w + w_off, k_b + h * 128,  k_h, N, 128, gE128 + 2 * gN128 };
        int nseg = 3, nblk = gE128 + 2 * gN128;
        if (h == 0) {
            P.s[3] = { msg_atom, skip_w, skip_b, outsum, N, 128, gE128 + 3 * gN128 };
            nseg = 4; nblk += gN128;
        }
        gemm_multi<false><<<nblk, 256, 0, stream>>>(P, nseg);
        attn_pass1<<<(N + 3) / 4, 256, 0, stream>>>(
            q_h, k_h, e_h, srcA, offsets, elist, alpha, N);
        gemm64<<<gN64, 256, 0, stream>>>(msg_atom, v_w + w_off, v_b + h * 128, v_h, N);
        attn_pass2<<<(N + 3) / 4, 256, 0, stream>>>(
            v_h, e_h, srcA, offsets, elist, alpha, outsum, N);
    }

    // 6. Set2Set + output projection (outsum == atom_hiddens)
    qv_kernel<<<1, 128, 0, stream>>>(lstm_bih, lstm_bhh, qvb);
    const int M = N / 20;  // 3000 molecules
    s2s_kernel<<<(M + 3) / 4, 256, 0, stream>>>(outsum, qvb, wo_w, wo_b, (float*)d_out, M);
}

// Round 9
// 2952.362 us; speedup vs baseline: 12.6224x; 6.9601x over previous
//
#include <hip/hip_runtime.h>
#include <hip/hip_bf16.h>

// ---------------- utility kernels ------------------------------------------
__global__ void zero_u32(unsigned int* __restrict__ p, long long n)
{
    long long i = (long long)blockIdx.x * 256 + threadIdx.x;
    if (i < n) p[i] = 0u;
}

__global__ void sentinel_f32(float* __restrict__ p, long long n, float v)
{
    long long i = (long long)blockIdx.x * 256 + threadIdx.x;
    if (i < n) p[i] = v;
}

__device__ __forceinline__ float4 load_f4_guard(const float* base, int gm, int M, int K, int kb)
{
    float4 v = make_float4(0.f, 0.f, 0.f, 0.f);
    if (gm < M) {
        const float* p = base + (size_t)gm * K + kb;
        if (kb + 4 <= K) v = *(const float4*)p;
        else {
            if (kb     < K) v.x = p[0];
            if (kb + 1 < K) v.y = p[1];
            if (kb + 2 < K) v.z = p[2];
            if (kb + 3 < K) v.w = p[3];
        }
    }
    return v;
}

// ---------------- multi-segment GEMM, BK=64, single-buffered -----------------
// C[M,128] = act(A[M,K] @ W[128,K]^T + bias?), up to 4 independent segments.
// 128x128 tile, 8x8/thread. BK=64: only ceil(K/64) K-steps -> few barriers.
// LDS 67.6 KB -> 2 blocks/CU; cross-block overlap hides staging.
struct GSeg {
    const float* A; const float* W; const float* bias; float* C;
    int M; int K; int bend;   // bend = exclusive block-id end of this segment
};
struct GParams { GSeg s[4]; };

template<bool RELU>
__global__ __launch_bounds__(256) void gemm_multi(GParams P, int nseg)
{
    __shared__ float As[64][132];   // [k][m]
    __shared__ float Ws[64][132];   // [k][n]
    const int b = blockIdx.x;
    int si = 0, bbeg = 0;
    while (si + 1 < nseg && b >= P.s[si].bend) { bbeg = P.s[si].bend; ++si; }
    const GSeg S = P.s[si];
    const int tid = threadIdx.x;
    const int tx = tid & 15, ty = tid >> 4;
    const int row0 = (b - bbeg) * 128;
    const int r  = tid >> 2;          // 0..63
    const int k4 = (tid & 3) * 4;     // 0,4,8,12 (within a k16 sub-chunk)
    const int nsteps = (S.K + 63) >> 6;

    float acc[8][8] = {};
    for (int s = 0; s < nsteps; ++s) {
        const int kbase = s * 64;
        // stage: 4 k16 sub-chunks x 2 row-halves, R6-proven bank-clean pattern
        for (int ks = 0; ks < 4; ++ks) {
            const int kk0 = ks * 16 + k4;
#pragma unroll
            for (int c = 0; c < 2; ++c) {
                int rr = r + c * 64;
                float4 av = load_f4_guard(S.A, row0 + rr, S.M, S.K, kbase + kk0);
                As[kk0 + 0][rr] = av.x; As[kk0 + 1][rr] = av.y;
                As[kk0 + 2][rr] = av.z; As[kk0 + 3][rr] = av.w;
                float4 wv = load_f4_guard(S.W, rr, 128, S.K, kbase + kk0);
                Ws[kk0 + 0][rr] = wv.x; Ws[kk0 + 1][rr] = wv.y;
                Ws[kk0 + 2][rr] = wv.z; Ws[kk0 + 3][rr] = wv.w;
            }
        }
        __syncthreads();
#pragma unroll
        for (int kk = 0; kk < 64; ++kk) {
            float4 a0 = *(const float4*)&As[kk][ty * 4];
            float4 a1 = *(const float4*)&As[kk][64 + ty * 4];
            float4 w0 = *(const float4*)&Ws[kk][tx * 4];
            float4 w1 = *(const float4*)&Ws[kk][64 + tx * 4];
            float a[8] = {a0.x, a0.y, a0.z, a0.w, a1.x, a1.y, a1.z, a1.w};
            float w[8] = {w0.x, w0.y, w0.z, w0.w, w1.x, w1.y, w1.z, w1.w};
#pragma unroll
            for (int i = 0; i < 8; ++i)
#pragma unroll
                for (int j = 0; j < 8; ++j)
                    acc[i][j] += a[i] * w[j];
        }
        __syncthreads();
    }
    float bs[8];
    if (S.bias) {
#pragma unroll
        for (int j = 0; j < 4; ++j) {
            bs[j]     = S.bias[tx * 4 + j];
            bs[j + 4] = S.bias[64 + tx * 4 + j];
        }
    } else {
#pragma unroll
        for (int j = 0; j < 8; ++j) bs[j] = 0.f;
    }
#pragma unroll
    for (int i = 0; i < 8; ++i) {
        int rr = (i < 4) ? (ty * 4 + i) : (64 + ty * 4 + i - 4);
        int gm = row0 + rr;
        if (gm >= S.M) continue;
#pragma unroll
        for (int jh = 0; jh < 2; ++jh) {
            float4 v;
            v.x = acc[i][jh * 4 + 0] + bs[jh * 4 + 0];
            v.y = acc[i][jh * 4 + 1] + bs[jh * 4 + 1];
            v.z = acc[i][jh * 4 + 2] + bs[jh * 4 + 2];
            v.w = acc[i][jh * 4 + 3] + bs[jh * 4 + 3];
            if (RELU) {
                v.x = fmaxf(v.x, 0.f); v.y = fmaxf(v.y, 0.f);
                v.z = fmaxf(v.z, 0.f); v.w = fmaxf(v.w, 0.f);
            }
            *(float4*)&S.C[(size_t)gm * 128 + jh * 64 + tx * 4] = v;
        }
    }
}

// ---- MP GEMM, BM=128, BK=64, gathered A:
// C[e] = relu(inb[e] + (ma[b2a[e]]-bond[b2revb[e]]) @ wh^T), K=128
__global__ __launch_bounds__(256) void gemm_mp(
    const float* __restrict__ ma, const float* __restrict__ bond,
    const int* __restrict__ b2a, const int* __restrict__ b2revb,
    const float* __restrict__ inb, const float* __restrict__ wh,
    float* __restrict__ C, int E)
{
    __shared__ float As[64][132];
    __shared__ float Ws[64][132];
    __shared__ int ia[128], ir[128];
    const int tid = threadIdx.x;
    const int tx = tid & 15, ty = tid >> 4;
    const int row0 = blockIdx.x * 128;
    const int r  = tid >> 2;
    const int k4 = (tid & 3) * 4;
    if (tid < 128) {
        int g = row0 + tid;
        ia[tid] = (g < E) ? b2a[g] : 0;
        ir[tid] = (g < E) ? b2revb[g] : 0;
    }
    __syncthreads();

    float acc[8][8] = {};
    for (int s = 0; s < 2; ++s) {
        const int kbase = s * 64;
        for (int ks = 0; ks < 4; ++ks) {
            const int kk0 = ks * 16 + k4;
#pragma unroll
            for (int c = 0; c < 2; ++c) {
                int rr = r + c * 64;
                float4 x = *(const float4*)(ma   + (size_t)ia[rr] * 128 + kbase + kk0);
                float4 y = *(const float4*)(bond + (size_t)ir[rr] * 128 + kbase + kk0);
                As[kk0 + 0][rr] = x.x - y.x; As[kk0 + 1][rr] = x.y - y.y;
                As[kk0 + 2][rr] = x.z - y.z; As[kk0 + 3][rr] = x.w - y.w;
                float4 wv = *(const float4*)(wh + (size_t)rr * 128 + kbase + kk0);
                Ws[kk0 + 0][rr] = wv.x; Ws[kk0 + 1][rr] = wv.y;
                Ws[kk0 + 2][rr] = wv.z; Ws[kk0 + 3][rr] = wv.w;
            }
        }
        __syncthreads();
#pragma unroll
        for (int kk = 0; kk < 64; ++kk) {
            float4 a0 = *(const float4*)&As[kk][ty * 4];
            float4 a1 = *(const float4*)&As[kk][64 + ty * 4];
            float4 w0 = *(const float4*)&Ws[kk][tx * 4];
            float4 w1 = *(const float4*)&Ws[kk][64 + tx * 4];
            float a[8] = {a0.x, a0.y, a0.z, a0.w, a1.x, a1.y, a1.z, a1.w};
            float w[8] = {w0.x, w0.y, w0.z, w0.w, w1.x, w1.y, w1.z, w1.w};
#pragma unroll
            for (int i = 0; i < 8; ++i)
#pragma unroll
                for (int j = 0; j < 8; ++j)
                    acc[i][j] += a[i] * w[j];
        }
        __syncthreads();
    }
#pragma unroll
    for (int i = 0; i < 8; ++i) {
        int rr = (i < 4) ? (ty * 4 + i) : (64 + ty * 4 + i - 4);
        int gm = row0 + rr;
        if (gm >= E) continue;
#pragma unroll
        for (int jh = 0; jh < 2; ++jh) {
            int cc = jh * 64 + tx * 4;
            float4 o = *(const float4*)&inb[(size_t)gm * 128 + cc];
            float4 v;
            v.x = fmaxf(acc[i][jh * 4 + 0] + o.x, 0.f);
            v.y = fmaxf(acc[i][jh * 4 + 1] + o.y, 0.f);
            v.z = fmaxf(acc[i][jh * 4 + 2] + o.z, 0.f);
            v.w = fmaxf(acc[i][jh * 4 + 3] + o.w, 0.f);
            *(float4*)&C[(size_t)gm * 128 + cc] = v;
        }
    }
}

// ---------------- aggregation (float4, 8 nodes/block) ------------------------
__global__ __launch_bounds__(256) void agg_kernel(
    const float* __restrict__ bond, const int* __restrict__ a2b,
    float* __restrict__ ma, int N)
{
    int n = blockIdx.x * 8 + (threadIdx.x >> 5);
    if (n >= N) return;
    int d4 = (threadIdx.x & 31) * 4;
    const int* ix = a2b + (size_t)n * 6;
    float4 s = make_float4(0.f, 0.f, 0.f, 0.f);
    float4 mx = make_float4(-3.0e38f, -3.0e38f, -3.0e38f, -3.0e38f);
#pragma unroll
    for (int j = 0; j < 6; ++j) {
        float4 v = *(const float4*)(bond + (size_t)ix[j] * 128 + d4);
        s.x += v.x; s.y += v.y; s.z += v.z; s.w += v.w;
        mx.x = fmaxf(mx.x, v.x); mx.y = fmaxf(mx.y, v.y);
        mx.z = fmaxf(mx.z, v.z); mx.w = fmaxf(mx.w, v.w);
    }
    float* mp = ma + (size_t)n * 128 + d4;
    float4 o = *(const float4*)mp;
    o.x += s.x * mx.x; o.y += s.y * mx.y; o.z += s.z * mx.z; o.w += s.w * mx.w;
    *(float4*)mp = o;
}

// ---------------- CSR build over dst ----------------------------------------
__global__ void count_kernel(const int* __restrict__ dst, int* __restrict__ counts, int E)
{
    int e = blockIdx.x * 256 + threadIdx.x;
    if (e < E) atomicAdd(&counts[dst[e]], 1);
}

__global__ __launch_bounds__(1024) void scan_kernel(
    const int* __restrict__ counts, int* __restrict__ offsets, int N)
{
    __shared__ int sums[1024];
    int t = threadIdx.x;
    int chunk = (N + 1023) >> 10;
    int b = t * chunk;
    int e = b + chunk; if (e > N) e = N;
    int s = 0;
    for (int i = b; i < e; ++i) s += counts[i];
    sums[t] = s;
    __syncthreads();
    for (int off = 1; off < 1024; off <<= 1) {
        int v = (t >= off) ? sums[t - off] : 0;
        __syncthreads();
        sums[t] += v;
        __syncthreads();
    }
    int run = sums[t] - s;
    for (int i = b; i < e; ++i) { offsets[i] = run; run += counts[i]; }
    if (t == 1023) offsets[N] = sums[1023];
}

__global__ void fill_kernel(const int* __restrict__ dst, const int* __restrict__ offsets,
                            int* __restrict__ cursor, int* __restrict__ elist, int E)
{
    int e = blockIdx.x * 256 + threadIdx.x;
    if (e < E) {
        int d = dst[e];
        int pos = offsets[d] + atomicAdd(&cursor[d], 1);
        elist[pos] = e;
    }
}

// ---------------- attention pass 1: logits -> normalized alpha --------------
__global__ __launch_bounds__(256) void attn_pass1(
    const float* __restrict__ qh, const float* __restrict__ kh,
    const float* __restrict__ eh, const int* __restrict__ srcA,
    const int* __restrict__ offs, const int* __restrict__ elist,
    float* __restrict__ alpha, int N)
{
    int n = blockIdx.x * 4 + (threadIdx.x >> 6);
    if (n >= N) return;
    int l = threadIdx.x & 63;
    const float rs = 0.08838834764831845f;  // 1/sqrt(128)
    float2 q2 = ((const float2*)(qh + (size_t)n * 128))[l];
    int b = offs[n], en = offs[n + 1];
    float m = -3.0e38f, denom = 0.f;
    int ie = b;
    for (; ie + 2 <= en; ie += 2) {
        int e0 = elist[ie], e1 = elist[ie + 1];
        int s0 = srcA[e0], s1 = srcA[e1];
        float2 k0v = ((const float2*)(kh + (size_t)s0 * 128))[l];
        float2 e0v = ((const float2*)(eh + (size_t)e0 * 128))[l];
        float2 k1v = ((const float2*)(kh + (size_t)s1 * 128))[l];
        float2 e1v = ((const float2*)(eh + (size_t)e1 * 128))[l];
        float p0 = q2.x * (k0v.x + e0v.x) + q2.y * (k0v.y + e0v.y);
        float p1 = q2.x * (k1v.x + e1v.x) + q2.y * (k1v.y + e1v.y);
        p0 += __shfl_xor(p0, 1);  p1 += __shfl_xor(p1, 1);
        p0 += __shfl_xor(p0, 2);  p1 += __shfl_xor(p1, 2);
        p0 += __shfl_xor(p0, 4);  p1 += __shfl_xor(p1, 4);
        p0 += __shfl_xor(p0, 8);  p1 += __shfl_xor(p1, 8);
        p0 += __shfl_xor(p0, 16); p1 += __shfl_xor(p1, 16);
        p0 += __shfl_xor(p0, 32); p1 += __shfl_xor(p1, 32);
        float l0 = p0 * rs, l1 = p1 * rs;
        if (l == 0) { alpha[ie] = l0; alpha[ie + 1] = l1; }
        float mn = fmaxf(m, fmaxf(l0, l1));
        float sc = __expf(m - mn);
        denom = denom * sc + __expf(l0 - mn) + __expf(l1 - mn);
        m = mn;
    }
    if (ie < en) {
        int e0 = elist[ie];
        int s0 = srcA[e0];
        float2 k0v = ((const float2*)(kh + (size_t)s0 * 128))[l];
        float2 e0v = ((const float2*)(eh + (size_t)e0 * 128))[l];
        float p0 = q2.x * (k0v.x + e0v.x) + q2.y * (k0v.y + e0v.y);
        p0 += __shfl_xor(p0, 1);  p0 += __shfl_xor(p0, 2);
        p0 += __shfl_xor(p0, 4);  p0 += __shfl_xor(p0, 8);
        p0 += __shfl_xor(p0, 16); p0 += __shfl_xor(p0, 32);
        float l0 = p0 * rs;
        if (l == 0) alpha[ie] = l0;
        float mn = fmaxf(m, l0);
        denom = denom * __expf(m - mn) + __expf(l0 - mn);
        m = mn;
    }
    if (l == 0 && b < en) {
        float invd = 1.f / (denom + 1e-16f);
        for (int i = b; i < en; ++i)
            alpha[i] = __expf(alpha[i] - m) * invd;
    }
}

// ---------------- attention pass 2: outsum += 0.125 * alpha*(v[src]+eattr) --
__global__ __launch_bounds__(256) void attn_pass2(
    const float* __restrict__ vh, const float* __restrict__ eh,
    const int* __restrict__ srcA, const int* __restrict__ offs,
    const int* __restrict__ elist, const float* __restrict__ alpha,
    float* __restrict__ outsum, int N)
{
    int n = blockIdx.x * 4 + (threadIdx.x >> 6);
    if (n >= N) return;
    int l = threadIdx.x & 63;
    int b = offs[n], en = offs[n + 1];
    float a0 = 0.f, a1 = 0.f;
    int ie = b;
    for (; ie + 2 <= en; ie += 2) {
        int e0 = elist[ie], e1 = elist[ie + 1];
        int s0 = srcA[e0], s1 = srcA[e1];
        float al0 = alpha[ie], al1 = alpha[ie + 1];
        float2 v0 = ((const float2*)(vh + (size_t)s0 * 128))[l];
        float2 e0v = ((const float2*)(eh + (size_t)e0 * 128))[l];
        float2 v1 = ((const float2*)(vh + (size_t)s1 * 128))[l];
        float2 e1v = ((const float2*)(eh + (size_t)e1 * 128))[l];
        a0 += al0 * (v0.x + e0v.x) + al1 * (v1.x + e1v.x);
        a1 += al0 * (v0.y + e0v.y) + al1 * (v1.y + e1v.y);
    }
    if (ie < en) {
        int e0 = elist[ie];
        int s0 = srcA[e0];
        float al0 = alpha[ie];
        float2 v0 = ((const float2*)(vh + (size_t)s0 * 128))[l];
        float2 e0v = ((const float2*)(eh + (size_t)e0 * 128))[l];
        a0 += al0 * (v0.x + e0v.x);
        a1 += al0 * (v0.y + e0v.y);
    }
    float* op = outsum + (size_t)n * 128 + 2 * l;
    op[0] += 0.125f * a0;
    op[1] += 0.125f * a1;
}

// ---------------- Set2Set ----------------------------------------------------
__global__ void qv_kernel(const float* __restrict__ bih, const float* __restrict__ bhh,
                          float* __restrict__ qv)
{
    int t = threadIdx.x;  // 128 threads
    float gi = bih[t] + bhh[t];
    float gg = bih[256 + t] + bhh[256 + t];
    float go = bih[384 + t] + bhh[384 + t];
    float sig_i = 1.f / (1.f + __expf(-gi));
    float c = sig_i * tanhf(gg);
    float sig_o = 1.f / (1.f + __expf(-go));
    qv[t] = sig_o * tanhf(c);
}

__global__ __launch_bounds__(256) void s2s_kernel(
    const float* __restrict__ ah, const float* __restrict__ qv,
    const float* __restrict__ wo_w, const float* __restrict__ wo_b,
    float* __restrict__ out, int M)
{
    __shared__ float rsh[4][128];
    __shared__ float qsh[128];
    int wv = threadIdx.x >> 6, l = threadIdx.x & 63;
    if (threadIdx.x < 128) qsh[threadIdx.x] = qv[threadIdx.x];
    __syncthreads();
    int m = blockIdx.x * 4 + wv;
    bool active = (m < M);
    if (active) {
        const float* x = ah + (size_t)m * 20 * 128;
        float q0 = qsh[2 * l], q1 = qsh[2 * l + 1];
        float e[20]; float mx = -3.0e38f;
#pragma unroll
        for (int a = 0; a < 20; ++a) {
            float part = x[a * 128 + 2 * l] * q0 + x[a * 128 + 2 * l + 1] * q1;
            part += __shfl_xor(part, 1);  part += __shfl_xor(part, 2);
            part += __shfl_xor(part, 4);  part += __shfl_xor(part, 8);
            part += __shfl_xor(part, 16); part += __shfl_xor(part, 32);
            e[a] = part; mx = fmaxf(mx, part);
        }
        float sum = 0.f;
#pragma unroll
        for (int a = 0; a < 20; ++a) { e[a] = __expf(e[a] - mx); sum += e[a]; }
        float invs = 1.f / (sum + 1e-16f);
        float r0 = 0.f, r1 = 0.f;
#pragma unroll
        for (int a = 0; a < 20; ++a) {
            float w = e[a] * invs;
            r0 += w * x[a * 128 + 2 * l];
            r1 += w * x[a * 128 + 2 * l + 1];
        }
        rsh[wv][2 * l] = r0; rsh[wv][2 * l + 1] = r1;
    }
    __syncthreads();
    if (active) {
#pragma unroll
        for (int dd = 0; dd < 2; ++dd) {
            int d = 2 * l + dd;
            float acc = wo_b[d];
            const float* wr = wo_w + (size_t)d * 256;
            for (int j = 0; j < 128; ++j)
                acc += wr[j] * qsh[j] + wr[128 + j] * rsh[wv][j];
            out[(size_t)m * 128 + d] = acc;
        }
    }
}

// ---------------- launch -----------------------------------------------------
extern "C" void kernel_launch(void* const* d_in, const int* in_sizes, int n_in,
                              void* d_out, int out_size, void* d_ws, size_t ws_size,
                              hipStream_t stream)
{
    const int N = 60000, E = 120000, FA = 133, FB = 147;
    const float* f_atoms  = (const float*)d_in[0];
    const float* f_bonds  = (const float*)d_in[1];
    const float* wi_atom  = (const float*)d_in[2];
    const float* wi_bond  = (const float*)d_in[3];
    const float* wh[3]    = { (const float*)d_in[4], (const float*)d_in[5], (const float*)d_in[6] };
    const float* q_w      = (const float*)d_in[7];
    const float* q_b      = (const float*)d_in[8];
    const float* k_w      = (const float*)d_in[9];
    const float* k_b      = (const float*)d_in[10];
    const float* v_w      = (const float*)d_in[11];
    const float* v_b      = (const float*)d_in[12];
    const float* e_w      = (const float*)d_in[13];
    const float* skip_w   = (const float*)d_in[14];
    const float* skip_b   = (const float*)d_in[15];
    const float* lstm_bih = (const float*)d_in[18];
    const float* lstm_bhh = (const float*)d_in[19];
    const float* wo_w     = (const float*)d_in[20];
    const float* wo_b     = (const float*)d_in[21];
    const int* a2b    = (const int*)d_in[22];
    const int* b2a    = (const int*)d_in[23];
    const int* b2revb = (const int*)d_in[24];
    const int* bonds  = (const int*)d_in[25];
    const int* srcA = bonds;
    const int* dstA = bonds + E;

    // ---- workspace plan (~248 MB; ws_size ~256 MiB) ----
    const size_t NB = (size_t)N * 128;
    const size_t EB = (size_t)E * 128;
    char* ws = (char*)d_ws;
    size_t off = 0;
    auto alloc = [&](size_t bytes) -> char* {
        char* p = ws + off; off += (bytes + 255) & ~255ULL; return p;
    };
    float* msg_atom = (float*)alloc(NB * 4);   // atoms, whole run
    float* B1       = (float*)alloc(EB * 4);   // input_bond -> [q|k] -> [v|k]
    float* B2       = (float*)alloc(EB * 4);   // bond ping (final msg_bond)
    float* B3       = (float*)alloc(EB * 4);   // bond pong -> eattr_h
    float* outsum   = (float*)alloc(NB * 4);   // skip-init, attn accum, = ah
    float* alpha    = (float*)alloc((size_t)E * 4);
    int* counts  = (int*)alloc((size_t)N * 2 * 4);   // counts | cursor contiguous
    int* cursor  = counts + N;
    int* offsets = (int*)alloc((size_t)(N + 1) * 4);
    int* elist   = (int*)alloc((size_t)E * 4);
    float* qvb   = (float*)alloc(128 * 4);

    if (off > ws_size) {
        long long n = out_size;
        sentinel_f32<<<(int)((n + 255) / 256), 256, 0, stream>>>((float*)d_out, n, 1.0e9f);
        return;
    }

    float* q_h = B1;            // [N,128]
    float* k_h = B1 + NB;       // [N,128]
    float* v_h = B1;            // [N,128] overwrites q after pass1
    float* e_h = B3;            // [E,128]

    const int gN128 = (N + 127) / 128;   // 469
    const int gE128 = (E + 127) / 128;   // 938

    // 0. zero CSR state (graph-capture/replay-safe)
    zero_u32<<<(2 * N + 255) / 256, 256, 0, stream>>>((unsigned int*)counts, 2 * N);

    // 1. input projections (one merged launch, per-segment K)
    {
        GParams P{};
        P.s[0] = { f_atoms, wi_atom, nullptr, msg_atom, N, FA, gN128 };
        P.s[1] = { f_bonds, wi_bond, nullptr, B1,       E, FB, gN128 + gE128 };
        gemm_multi<true><<<gN128 + gE128, 256, 0, stream>>>(P, 2);
    }

    // 2. CSR over dst
    count_kernel<<<(E + 255) / 256, 256, 0, stream>>>(dstA, counts, E);
    scan_kernel<<<1, 1024, 0, stream>>>(counts, offsets, N);
    fill_kernel<<<(E + 255) / 256, 256, 0, stream>>>(dstA, offsets, cursor, elist, E);

    // 3. message passing: B1(input) -> B2 -> B3 -> B2 (gather-fused GEMM)
    const float* cur = B1;
    float* nxt[3] = { B2, B3, B2 };
    for (int it = 0; it < 3; ++it) {
        agg_kernel<<<(N + 7) / 8, 256, 0, stream>>>(cur, a2b, msg_atom, N);
        gemm_mp<<<gE128, 256, 0, stream>>>(
            msg_atom, cur, b2a, b2revb, B1, wh[it], nxt[it], E);
        cur = nxt[it];
    }
    // final message_bond = B2; B1, B3 now dead

    // 4./5. TransformerConv per head; skip-GEMM rides in head 0's launch
    for (int h = 0; h < 8; ++h) {
        const size_t w_off = (size_t)h * 128 * 128;
        GParams P{};
        P.s[0] = { B2,       e_w + w_off, nullptr,        e_h, E, 128, gE128 };
        P.s[1] = { msg_atom, q_w + w_off, q_b + h * 128,  q_h, N, 128, gE128 + gN128 };
        P.s[2] = { msg_atom, k_w + w_off, k_b + h * 128,  k_h, N, 128, gE128 + 2 * gN128 };
        int nseg = 3, nblk = gE128 + 2 * gN128;
        if (h == 0) {
            P.s[3] = { msg_atom, skip_w, skip_b, outsum, N, 128, gE128 + 3 * gN128 };
            nseg = 4; nblk += gN128;
        }
        gemm_multi<false><<<nblk, 256, 0, stream>>>(P, nseg);
        attn_pass1<<<(N + 3) / 4, 256, 0, stream>>>(
            q_h, k_h, e_h, srcA, offsets, elist, alpha, N);
        {
            GParams PV{};
            PV.s[0] = { msg_atom, v_w + w_off, v_b + h * 128, v_h, N, 128, gN128 };
            gemm_multi<false><<<gN128, 256, 0, stream>>>(PV, 1);
        }
        attn_pass2<<<(N + 3) / 4, 256, 0, stream>>>(
            v_h, e_h, srcA, offsets, elist, alpha, outsum, N);
    }

    // 6. Set2Set + output projection (outsum == atom_hiddens)
    qv_kernel<<<1, 128, 0, stream>>>(lstm_bih, lstm_bhh, qvb);
    const int M = N / 20;  // 3000 molecules
    s2s_kernel<<<(M + 3) / 4, 256, 0, stream>>>(outsum, qvb, wo_w, wo_b, (float*)d_out, M);
}

// Round 10
// 2232.364 us; speedup vs baseline: 16.6935x; 1.3225x over previous
//
#include <hip/hip_runtime.h>
#include <hip/hip_bf16.h>

// ---------------- utility kernels ------------------------------------------
__global__ void zero_u32(unsigned int* __restrict__ p, long long n)
{
    long long i = (long long)blockIdx.x * 256 + threadIdx.x;
    if (i < n) p[i] = 0u;
}

__global__ void sentinel_f32(float* __restrict__ p, long long n, float v)
{
    long long i = (long long)blockIdx.x * 256 + threadIdx.x;
    if (i < n) p[i] = v;
}

__device__ __forceinline__ float4 load_f4_guard(const float* base, int gm, int M, int K, int kb)
{
    float4 v = make_float4(0.f, 0.f, 0.f, 0.f);
    if (gm < M) {
        const float* p = base + (size_t)gm * K + kb;
        if (kb + 4 <= K) v = *(const float4*)p;
        else {
            if (kb     < K) v.x = p[0];
            if (kb + 1 < K) v.y = p[1];
            if (kb + 2 < K) v.z = p[2];
            if (kb + 3 < K) v.w = p[3];
        }
    }
    return v;
}

// ---------------- multi-segment GEMM, BM=64, 4x8/thread, BK=16 ---------------
// C[M,128] = act(A[M,K] @ W[128,K]^T + bias?), up to 4 independent segments.
// Small footprint by design: ~32 acc VGPRs (<=64 total -> up to 32 waves/CU),
// LDS 12.5 KB. R6 data: smaller tiles + more resident waves won every time.
struct GSeg {
    const float* A; const float* W; const float* bias; float* C;
    int M; int K; int bend;   // bend = exclusive block-id end of this segment
};
struct GParams { GSeg s[4]; };

template<bool RELU>
__global__ __launch_bounds__(256) void gemm_multi(GParams P, int nseg)
{
    __shared__ float As[16][68];    // [k][m], 64 rows + pad
    __shared__ float Ws[16][132];   // [k][n], 128 cols + pad
    const int b = blockIdx.x;
    int si = 0, bbeg = 0;
    while (si + 1 < nseg && b >= P.s[si].bend) { bbeg = P.s[si].bend; ++si; }
    const GSeg S = P.s[si];
    const int tid = threadIdx.x;
    const int tx = tid & 15, ty = tid >> 4;
    const int row0 = (b - bbeg) * 64;
    const int r  = tid >> 2;          // 0..63
    const int k4 = (tid & 3) * 4;     // 0,4,8,12

    float acc[4][8] = {};
    for (int k0 = 0; k0 < S.K; k0 += 16) {
        {
            float4 av = load_f4_guard(S.A, row0 + r, S.M, S.K, k0 + k4);
            As[k4 + 0][r] = av.x; As[k4 + 1][r] = av.y;
            As[k4 + 2][r] = av.z; As[k4 + 3][r] = av.w;
        }
#pragma unroll
        for (int c = 0; c < 2; ++c) {
            int rr = r + c * 64;
            float4 wv = load_f4_guard(S.W, rr, 128, S.K, k0 + k4);
            Ws[k4 + 0][rr] = wv.x; Ws[k4 + 1][rr] = wv.y;
            Ws[k4 + 2][rr] = wv.z; Ws[k4 + 3][rr] = wv.w;
        }
        __syncthreads();
#pragma unroll
        for (int kk = 0; kk < 16; ++kk) {
            float4 a0 = *(const float4*)&As[kk][ty * 4];
            float4 w0 = *(const float4*)&Ws[kk][tx * 4];
            float4 w1 = *(const float4*)&Ws[kk][64 + tx * 4];
            float a[4] = {a0.x, a0.y, a0.z, a0.w};
            float w[8] = {w0.x, w0.y, w0.z, w0.w, w1.x, w1.y, w1.z, w1.w};
#pragma unroll
            for (int i = 0; i < 4; ++i)
#pragma unroll
                for (int j = 0; j < 8; ++j)
                    acc[i][j] += a[i] * w[j];
        }
        __syncthreads();
    }
    float bs[8];
    if (S.bias) {
#pragma unroll
        for (int j = 0; j < 4; ++j) {
            bs[j]     = S.bias[tx * 4 + j];
            bs[j + 4] = S.bias[64 + tx * 4 + j];
        }
    } else {
#pragma unroll
        for (int j = 0; j < 8; ++j) bs[j] = 0.f;
    }
#pragma unroll
    for (int i = 0; i < 4; ++i) {
        int gm = row0 + ty * 4 + i;
        if (gm >= S.M) continue;
#pragma unroll
        for (int jh = 0; jh < 2; ++jh) {
            float4 v;
            v.x = acc[i][jh * 4 + 0] + bs[jh * 4 + 0];
            v.y = acc[i][jh * 4 + 1] + bs[jh * 4 + 1];
            v.z = acc[i][jh * 4 + 2] + bs[jh * 4 + 2];
            v.w = acc[i][jh * 4 + 3] + bs[jh * 4 + 3];
            if (RELU) {
                v.x = fmaxf(v.x, 0.f); v.y = fmaxf(v.y, 0.f);
                v.z = fmaxf(v.z, 0.f); v.w = fmaxf(v.w, 0.f);
            }
            *(float4*)&S.C[(size_t)gm * 128 + jh * 64 + tx * 4] = v;
        }
    }
}

// ---- MP GEMM, BM=64, BK=16, gathered A (R6-proven):
// C[e] = relu(inb[e] + (ma[b2a[e]]-bond[b2revb[e]]) @ wh^T), K=128
__global__ __launch_bounds__(256) void gemm_mp(
    const float* __restrict__ ma, const float* __restrict__ bond,
    const int* __restrict__ b2a, const int* __restrict__ b2revb,
    const float* __restrict__ inb, const float* __restrict__ wh,
    float* __restrict__ C)
{
    __shared__ float As[16][68];
    __shared__ float Ws[16][132];
    __shared__ int ia[64], ir[64];
    const int tid = threadIdx.x;
    const int tx = tid & 15, ty = tid >> 4;
    const int row0 = blockIdx.x * 64;
    const int r  = tid >> 2;
    const int k4 = (tid & 3) * 4;
    if (tid < 64)       ia[tid]      = b2a[row0 + tid];
    else if (tid < 128) ir[tid - 64] = b2revb[row0 + tid - 64];
    __syncthreads();
    float acc[4][8] = {};
    for (int k0 = 0; k0 < 128; k0 += 16) {
        {
            float4 x = *(const float4*)(ma   + (size_t)ia[r] * 128 + k0 + k4);
            float4 y = *(const float4*)(bond + (size_t)ir[r] * 128 + k0 + k4);
            As[k4 + 0][r] = x.x - y.x; As[k4 + 1][r] = x.y - y.y;
            As[k4 + 2][r] = x.z - y.z; As[k4 + 3][r] = x.w - y.w;
        }
#pragma unroll
        for (int c = 0; c < 2; ++c) {
            int rr = r + c * 64;
            float4 wv = *(const float4*)(wh + (size_t)rr * 128 + k0 + k4);
            Ws[k4 + 0][rr] = wv.x; Ws[k4 + 1][rr] = wv.y;
            Ws[k4 + 2][rr] = wv.z; Ws[k4 + 3][rr] = wv.w;
        }
        __syncthreads();
#pragma unroll
        for (int kk = 0; kk < 16; ++kk) {
            float4 a0 = *(const float4*)&As[kk][ty * 4];
            float4 w0 = *(const float4*)&Ws[kk][tx * 4];
            float4 w1 = *(const float4*)&Ws[kk][64 + tx * 4];
            float a[4] = {a0.x, a0.y, a0.z, a0.w};
            float w[8] = {w0.x, w0.y, w0.z, w0.w, w1.x, w1.y, w1.z, w1.w};
#pragma unroll
            for (int i = 0; i < 4; ++i)
#pragma unroll
                for (int j = 0; j < 8; ++j)
                    acc[i][j] += a[i] * w[j];
        }
        __syncthreads();
    }
#pragma unroll
    for (int i = 0; i < 4; ++i) {
        int gm = row0 + ty * 4 + i;
#pragma unroll
        for (int jh = 0; jh < 2; ++jh) {
            int cc = jh * 64 + tx * 4;
            float4 o = *(const float4*)&inb[(size_t)gm * 128 + cc];
            float4 v;
            v.x = fmaxf(acc[i][jh * 4 + 0] + o.x, 0.f);
            v.y = fmaxf(acc[i][jh * 4 + 1] + o.y, 0.f);
            v.z = fmaxf(acc[i][jh * 4 + 2] + o.z, 0.f);
            v.w = fmaxf(acc[i][jh * 4 + 3] + o.w, 0.f);
            *(float4*)&C[(size_t)gm * 128 + cc] = v;
        }
    }
}

// ---------------- aggregation (float4, 8 nodes/block) ------------------------
__global__ __launch_bounds__(256) void agg_kernel(
    const float* __restrict__ bond, const int* __restrict__ a2b,
    float* __restrict__ ma, int N)
{
    int n = blockIdx.x * 8 + (threadIdx.x >> 5);
    if (n >= N) return;
    int d4 = (threadIdx.x & 31) * 4;
    const int* ix = a2b + (size_t)n * 6;
    float4 s = make_float4(0.f, 0.f, 0.f, 0.f);
    float4 mx = make_float4(-3.0e38f, -3.0e38f, -3.0e38f, -3.0e38f);
#pragma unroll
    for (int j = 0; j < 6; ++j) {
        float4 v = *(const float4*)(bond + (size_t)ix[j] * 128 + d4);
        s.x += v.x; s.y += v.y; s.z += v.z; s.w += v.w;
        mx.x = fmaxf(mx.x, v.x); mx.y = fmaxf(mx.y, v.y);
        mx.z = fmaxf(mx.z, v.z); mx.w = fmaxf(mx.w, v.w);
    }
    float* mp = ma + (size_t)n * 128 + d4;
    float4 o = *(const float4*)mp;
    o.x += s.x * mx.x; o.y += s.y * mx.y; o.z += s.z * mx.z; o.w += s.w * mx.w;
    *(float4*)mp = o;
}

// ---------------- CSR build over dst ----------------------------------------
__global__ void count_kernel(const int* __restrict__ dst, int* __restrict__ counts, int E)
{
    int e = blockIdx.x * 256 + threadIdx.x;
    if (e < E) atomicAdd(&counts[dst[e]], 1);
}

__global__ __launch_bounds__(1024) void scan_kernel(
    const int* __restrict__ counts, int* __restrict__ offsets, int N)
{
    __shared__ int sums[1024];
    int t = threadIdx.x;
    int chunk = (N + 1023) >> 10;
    int b = t * chunk;
    int e = b + chunk; if (e > N) e = N;
    int s = 0;
    for (int i = b; i < e; ++i) s += counts[i];
    sums[t] = s;
    __syncthreads();
    for (int off = 1; off < 1024; off <<= 1) {
        int v = (t >= off) ? sums[t - off] : 0;
        __syncthreads();
        sums[t] += v;
        __syncthreads();
    }
    int run = sums[t] - s;
    for (int i = b; i < e; ++i) { offsets[i] = run; run += counts[i]; }
    if (t == 1023) offsets[N] = sums[1023];
}

__global__ void fill_kernel(const int* __restrict__ dst, const int* __restrict__ offsets,
                            int* __restrict__ cursor, int* __restrict__ elist, int E)
{
    int e = blockIdx.x * 256 + threadIdx.x;
    if (e < E) {
        int d = dst[e];
        int pos = offsets[d] + atomicAdd(&cursor[d], 1);
        elist[pos] = e;
    }
}

// ---------------- attention pass 1: logits -> normalized alpha --------------
__global__ __launch_bounds__(256) void attn_pass1(
    const float* __restrict__ qh, const float* __restrict__ kh,
    const float* __restrict__ eh, const int* __restrict__ srcA,
    const int* __restrict__ offs, const int* __restrict__ elist,
    float* __restrict__ alpha, int N)
{
    int n = blockIdx.x * 4 + (threadIdx.x >> 6);
    if (n >= N) return;
    int l = threadIdx.x & 63;
    const float rs = 0.08838834764831845f;  // 1/sqrt(128)
    float2 q2 = ((const float2*)(qh + (size_t)n * 128))[l];
    int b = offs[n], en = offs[n + 1];
    float m = -3.0e38f, denom = 0.f;
    int ie = b;
    for (; ie + 2 <= en; ie += 2) {
        int e0 = elist[ie], e1 = elist[ie + 1];
        int s0 = srcA[e0], s1 = srcA[e1];
        float2 k0v = ((const float2*)(kh + (size_t)s0 * 128))[l];
        float2 e0v = ((const float2*)(eh + (size_t)e0 * 128))[l];
        float2 k1v = ((const float2*)(kh + (size_t)s1 * 128))[l];
        float2 e1v = ((const float2*)(eh + (size_t)e1 * 128))[l];
        float p0 = q2.x * (k0v.x + e0v.x) + q2.y * (k0v.y + e0v.y);
        float p1 = q2.x * (k1v.x + e1v.x) + q2.y * (k1v.y + e1v.y);
        p0 += __shfl_xor(p0, 1);  p1 += __shfl_xor(p1, 1);
        p0 += __shfl_xor(p0, 2);  p1 += __shfl_xor(p1, 2);
        p0 += __shfl_xor(p0, 4);  p1 += __shfl_xor(p1, 4);
        p0 += __shfl_xor(p0, 8);  p1 += __shfl_xor(p1, 8);
        p0 += __shfl_xor(p0, 16); p1 += __shfl_xor(p1, 16);
        p0 += __shfl_xor(p0, 32); p1 += __shfl_xor(p1, 32);
        float l0 = p0 * rs, l1 = p1 * rs;
        if (l == 0) { alpha[ie] = l0; alpha[ie + 1] = l1; }
        float mn = fmaxf(m, fmaxf(l0, l1));
        float sc = __expf(m - mn);
        denom = denom * sc + __expf(l0 - mn) + __expf(l1 - mn);
        m = mn;
    }
    if (ie < en) {
        int e0 = elist[ie];
        int s0 = srcA[e0];
        float2 k0v = ((const float2*)(kh + (size_t)s0 * 128))[l];
        float2 e0v = ((const float2*)(eh + (size_t)e0 * 128))[l];
        float p0 = q2.x * (k0v.x + e0v.x) + q2.y * (k0v.y + e0v.y);
        p0 += __shfl_xor(p0, 1);  p0 += __shfl_xor(p0, 2);
        p0 += __shfl_xor(p0, 4);  p0 += __shfl_xor(p0, 8);
        p0 += __shfl_xor(p0, 16); p0 += __shfl_xor(p0, 32);
        float l0 = p0 * rs;
        if (l == 0) alpha[ie] = l0;
        float mn = fmaxf(m, l0);
        denom = denom * __expf(m - mn) + __expf(l0 - mn);
        m = mn;
    }
    if (l == 0 && b < en) {
        float invd = 1.f / (denom + 1e-16f);
        for (int i = b; i < en; ++i)
            alpha[i] = __expf(alpha[i] - m) * invd;
    }
}

// ---------------- attention pass 2: outsum += 0.125 * alpha*(v[src]+eattr) --
__global__ __launch_bounds__(256) void attn_pass2(
    const float* __restrict__ vh, const float* __restrict__ eh,
    const int* __restrict__ srcA, const int* __restrict__ offs,
    const int* __restrict__ elist, const float* __restrict__ alpha,
    float* __restrict__ outsum, int N)
{
    int n = blockIdx.x * 4 + (threadIdx.x >> 6);
    if (n >= N) return;
    int l = threadIdx.x & 63;
    int b = offs[n], en = offs[n + 1];
    float a0 = 0.f, a1 = 0.f;
    int ie = b;
    for (; ie + 2 <= en; ie += 2) {
        int e0 = elist[ie], e1 = elist[ie + 1];
        int s0 = srcA[e0], s1 = srcA[e1];
        float al0 = alpha[ie], al1 = alpha[ie + 1];
        float2 v0 = ((const float2*)(vh + (size_t)s0 * 128))[l];
        float2 e0v = ((const float2*)(eh + (size_t)e0 * 128))[l];
        float2 v1 = ((const float2*)(vh + (size_t)s1 * 128))[l];
        float2 e1v = ((const float2*)(eh + (size_t)e1 * 128))[l];
        a0 += al0 * (v0.x + e0v.x) + al1 * (v1.x + e1v.x);
        a1 += al0 * (v0.y + e0v.y) + al1 * (v1.y + e1v.y);
    }
    if (ie < en) {
        int e0 = elist[ie];
        int s0 = srcA[e0];
        float al0 = alpha[ie];
        float2 v0 = ((const float2*)(vh + (size_t)s0 * 128))[l];
        float2 e0v = ((const float2*)(eh + (size_t)e0 * 128))[l];
        a0 += al0 * (v0.x + e0v.x);
        a1 += al0 * (v0.y + e0v.y);
    }
    float* op = outsum + (size_t)n * 128 + 2 * l;
    op[0] += 0.125f * a0;
    op[1] += 0.125f * a1;
}

// ---------------- Set2Set ----------------------------------------------------
__global__ void qv_kernel(const float* __restrict__ bih, const float* __restrict__ bhh,
                          float* __restrict__ qv)
{
    int t = threadIdx.x;  // 128 threads
    float gi = bih[t] + bhh[t];
    float gg = bih[256 + t] + bhh[256 + t];
    float go = bih[384 + t] + bhh[384 + t];
    float sig_i = 1.f / (1.f + __expf(-gi));
    float c = sig_i * tanhf(gg);
    float sig_o = 1.f / (1.f + __expf(-go));
    qv[t] = sig_o * tanhf(c);
}

__global__ __launch_bounds__(256) void s2s_kernel(
    const float* __restrict__ ah, const float* __restrict__ qv,
    const float* __restrict__ wo_w, const float* __restrict__ wo_b,
    float* __restrict__ out, int M)
{
    __shared__ float rsh[4][128];
    __shared__ float qsh[128];
    int wv = threadIdx.x >> 6, l = threadIdx.x & 63;
    if (threadIdx.x < 128) qsh[threadIdx.x] = qv[threadIdx.x];
    __syncthreads();
    int m = blockIdx.x * 4 + wv;
    bool active = (m < M);
    if (active) {
        const float* x = ah + (size_t)m * 20 * 128;
        float q0 = qsh[2 * l], q1 = qsh[2 * l + 1];
        float e[20]; float mx = -3.0e38f;
#pragma unroll
        for (int a = 0; a < 20; ++a) {
            float part = x[a * 128 + 2 * l] * q0 + x[a * 128 + 2 * l + 1] * q1;
            part += __shfl_xor(part, 1);  part += __shfl_xor(part, 2);
            part += __shfl_xor(part, 4);  part += __shfl_xor(part, 8);
            part += __shfl_xor(part, 16); part += __shfl_xor(part, 32);
            e[a] = part; mx = fmaxf(mx, part);
        }
        float sum = 0.f;
#pragma unroll
        for (int a = 0; a < 20; ++a) { e[a] = __expf(e[a] - mx); sum += e[a]; }
        float invs = 1.f / (sum + 1e-16f);
        float r0 = 0.f, r1 = 0.f;
#pragma unroll
        for (int a = 0; a < 20; ++a) {
            float w = e[a] * invs;
            r0 += w * x[a * 128 + 2 * l];
            r1 += w * x[a * 128 + 2 * l + 1];
        }
        rsh[wv][2 * l] = r0; rsh[wv][2 * l + 1] = r1;
    }
    __syncthreads();
    if (active) {
#pragma unroll
        for (int dd = 0; dd < 2; ++dd) {
            int d = 2 * l + dd;
            float acc = wo_b[d];
            const float* wr = wo_w + (size_t)d * 256;
            for (int j = 0; j < 128; ++j)
                acc += wr[j] * qsh[j] + wr[128 + j] * rsh[wv][j];
            out[(size_t)m * 128 + d] = acc;
        }
    }
}

// ---------------- launch -----------------------------------------------------
extern "C" void kernel_launch(void* const* d_in, const int* in_sizes, int n_in,
                              void* d_out, int out_size, void* d_ws, size_t ws_size,
                              hipStream_t stream)
{
    const int N = 60000, E = 120000, FA = 133, FB = 147;
    const float* f_atoms  = (const float*)d_in[0];
    const float* f_bonds  = (const float*)d_in[1];
    const float* wi_atom  = (const float*)d_in[2];
    const float* wi_bond  = (const float*)d_in[3];
    const float* wh[3]    = { (const float*)d_in[4], (const float*)d_in[5], (const float*)d_in[6] };
    const float* q_w      = (const float*)d_in[7];
    const float* q_b      = (const float*)d_in[8];
    const float* k_w      = (const float*)d_in[9];
    const float* k_b      = (const float*)d_in[10];
    const float* v_w      = (const float*)d_in[11];
    const float* v_b      = (const float*)d_in[12];
    const float* e_w      = (const float*)d_in[13];
    const float* skip_w   = (const float*)d_in[14];
    const float* skip_b   = (const float*)d_in[15];
    const float* lstm_bih = (const float*)d_in[18];
    const float* lstm_bhh = (const float*)d_in[19];
    const float* wo_w     = (const float*)d_in[20];
    const float* wo_b     = (const float*)d_in[21];
    const int* a2b    = (const int*)d_in[22];
    const int* b2a    = (const int*)d_in[23];
    const int* b2revb = (const int*)d_in[24];
    const int* bonds  = (const int*)d_in[25];
    const int* srcA = bonds;
    const int* dstA = bonds + E;

    // ---- workspace plan (~248 MB; ws_size ~256 MiB) ----
    const size_t NB = (size_t)N * 128;
    const size_t EB = (size_t)E * 128;
    char* ws = (char*)d_ws;
    size_t off = 0;
    auto alloc = [&](size_t bytes) -> char* {
        char* p = ws + off; off += (bytes + 255) & ~255ULL; return p;
    };
    float* msg_atom = (float*)alloc(NB * 4);   // atoms, whole run
    float* B1       = (float*)alloc(EB * 4);   // input_bond -> [q|k] -> [v|k]
    float* B2       = (float*)alloc(EB * 4);   // bond ping (final msg_bond)
    float* B3       = (float*)alloc(EB * 4);   // bond pong -> eattr_h
    float* outsum   = (float*)alloc(NB * 4);   // skip-init, attn accum, = ah
    float* alpha    = (float*)alloc((size_t)E * 4);
    int* counts  = (int*)alloc((size_t)N * 2 * 4);   // counts | cursor contiguous
    int* cursor  = counts + N;
    int* offsets = (int*)alloc((size_t)(N + 1) * 4);
    int* elist   = (int*)alloc((size_t)E * 4);
    float* qvb   = (float*)alloc(128 * 4);

    if (off > ws_size) {
        long long n = out_size;
        sentinel_f32<<<(int)((n + 255) / 256), 256, 0, stream>>>((float*)d_out, n, 1.0e9f);
        return;
    }

    float* q_h = B1;            // [N,128]
    float* k_h = B1 + NB;       // [N,128]
    float* v_h = B1;            // [N,128] overwrites q after pass1
    float* e_h = B3;            // [E,128]

    const int gN64 = (N + 63) / 64;     // 938
    const int gE64 = E / 64;            // 1875 exact

    // 0. zero CSR state (graph-capture/replay-safe)
    zero_u32<<<(2 * N + 255) / 256, 256, 0, stream>>>((unsigned int*)counts, 2 * N);

    // 1. input projections (one merged launch, per-segment K)
    {
        GParams P{};
        P.s[0] = { f_atoms, wi_atom, nullptr, msg_atom, N, FA, gN64 };
        P.s[1] = { f_bonds, wi_bond, nullptr, B1,       E, FB, gN64 + gE64 };
        gemm_multi<true><<<gN64 + gE64, 256, 0, stream>>>(P, 2);
    }

    // 2. CSR over dst
    count_kernel<<<(E + 255) / 256, 256, 0, stream>>>(dstA, counts, E);
    scan_kernel<<<1, 1024, 0, stream>>>(counts, offsets, N);
    fill_kernel<<<(E + 255) / 256, 256, 0, stream>>>(dstA, offsets, cursor, elist, E);

    // 3. message passing: B1(input) -> B2 -> B3 -> B2 (gather-fused GEMM)
    const float* cur = B1;
    float* nxt[3] = { B2, B3, B2 };
    for (int it = 0; it < 3; ++it) {
        agg_kernel<<<(N + 7) / 8, 256, 0, stream>>>(cur, a2b, msg_atom, N);
        gemm_mp<<<gE64, 256, 0, stream>>>(
            msg_atom, cur, b2a, b2revb, B1, wh[it], nxt[it]);
        cur = nxt[it];
    }
    // final message_bond = B2; B1, B3 now dead

    // 4./5. TransformerConv per head; skip-GEMM rides in head 0's launch
    for (int h = 0; h < 8; ++h) {
        const size_t w_off = (size_t)h * 128 * 128;
        GParams P{};
        P.s[0] = { B2,       e_w + w_off, nullptr,        e_h, E, 128, gE64 };
        P.s[1] = { msg_atom, q_w + w_off, q_b + h * 128,  q_h, N, 128, gE64 + gN64 };
        P.s[2] = { msg_atom, k_w + w_off, k_b + h * 128,  k_h, N, 128, gE64 + 2 * gN64 };
        int nseg = 3, nblk = gE64 + 2 * gN64;
        if (h == 0) {
            P.s[3] = { msg_atom, skip_w, skip_b, outsum, N, 128, gE64 + 3 * gN64 };
            nseg = 4; nblk += gN64;
        }
        gemm_multi<false><<<nblk, 256, 0, stream>>>(P, nseg);
        attn_pass1<<<(N + 3) / 4, 256, 0, stream>>>(
            q_h, k_h, e_h, srcA, offsets, elist, alpha, N);
        {
            GParams PV{};
            PV.s[0] = { msg_atom, v_w + w_off, v_b + h * 128, v_h, N, 128, gN64 };
            gemm_multi<false><<<gN64, 256, 0, stream>>>(PV, 1);
        }
        attn_pass2<<<(N + 3) / 4, 256, 0, stream>>>(
            v_h, e_h, srcA, offsets, elist, alpha, outsum, N);
    }

    // 6. Set2Set + output projection (outsum == atom_hiddens)
    qv_kernel<<<1, 128, 0, stream>>>(lstm_bih, lstm_bhh, qvb);
    const int M = N / 20;  // 3000 molecules
    s2s_kernel<<<(M + 3) / 4, 256, 0, stream>>>(outsum, qvb, wo_w, wo_b, (float*)d_out, M);
}